// Round 4
// baseline (355.815 us; speedup 1.0000x reference)
//
#include <hip/hip_runtime.h>
#include <hip/hip_bf16.h>

// Problem constants
#define T_TOK 2048      // B*S
#define DDIM  1024
#define EEXP  8
#define KTOP  2
#define HDIM  2816
#define HSDIM 1536
#define BK    64
#define MT    256       // GEMM m-tile
#define NT_MAX 32       // worklist capacity: sum ceil(Ne/256) <= 24 routed + 8 shared

typedef float f32x4 __attribute__((ext_vector_type(4)));
typedef short bf16x8 __attribute__((ext_vector_type(8)));

__device__ __forceinline__ unsigned short f2bf(float f) {
    __hip_bfloat16 h = __float2bfloat16(f);
    return __builtin_bit_cast(unsigned short, h);
}

// async global->LDS, 16B per lane; LDS dest = wave-uniform base + lane*16
__device__ __forceinline__ void gload16(const unsigned short* g, unsigned short* l) {
    __builtin_amdgcn_global_load_lds(
        (const __attribute__((address_space(1))) unsigned int*)g,
        (__attribute__((address_space(3))) unsigned int*)l, 16, 0, 0);
}

// bijective chunked XCD remap (m204): hw block i -> XCD i%8; give each XCD a
// contiguous LOGICAL range so panel-sharing blocks co-reside on one L2.
__device__ __forceinline__ int xcd_chunk(int i, int nwg8) {
    return (i & 7) * nwg8 + (i >> 3);   // nwg8 = nwg/8, nwg % 8 == 0
}

// ---------------- small routing kernels ----------------

__global__ void init_k(int* counts, int* cursors) {
    if (threadIdx.x < EEXP) { counts[threadIdx.x] = 0; cursors[threadIdx.x] = 0; }
}

__global__ void gate_k(const float* __restrict__ X, const float* __restrict__ GW,
                       int* __restrict__ topi, float* __restrict__ topw,
                       int* __restrict__ counts) {
    int lane = threadIdx.x & 63;
    int t = blockIdx.x * 4 + (threadIdx.x >> 6);
    int e  = lane >> 3;
    int c8 = lane & 7;
    const float* xr = X + (size_t)t * DDIM;
    const float* gr = GW + (size_t)e * DDIM;
    float acc = 0.f;
#pragma unroll 8
    for (int j = 0; j < 32; j++) {
        int d = (c8 + 8 * j) * 4;
        float4 xv = *(const float4*)(xr + d);
        float4 gv = *(const float4*)(gr + d);
        acc += xv.x * gv.x + xv.y * gv.y + xv.z * gv.z + xv.w * gv.w;
    }
    acc += __shfl_xor(acc, 1);
    acc += __shfl_xor(acc, 2);
    acc += __shfl_xor(acc, 4);
    float p[8];
#pragma unroll
    for (int q = 0; q < 8; q++) p[q] = __shfl(acc, q * 8);
    float mx = p[0];
#pragma unroll
    for (int q = 1; q < 8; q++) mx = fmaxf(mx, p[q]);
    float s = 0.f;
#pragma unroll
    for (int q = 0; q < 8; q++) { p[q] = expf(p[q] - mx); s += p[q]; }
    float inv = 1.f / s;
#pragma unroll
    for (int q = 0; q < 8; q++) p[q] *= inv;
    float v1 = -1.f; int i1 = 0;
#pragma unroll
    for (int q = 0; q < 8; q++) { if (p[q] > v1) { v1 = p[q]; i1 = q; } }
    float v2 = -1.f; int i2 = 0;
#pragma unroll
    for (int q = 0; q < 8; q++) { if (q != i1 && p[q] > v2) { v2 = p[q]; i2 = q; } }
    if (lane == 0) {
        topi[2 * t] = i1; topi[2 * t + 1] = i2;
        topw[2 * t] = v1; topw[2 * t + 1] = v2;
        atomicAdd(&counts[i1], 1);
        atomicAdd(&counts[i2], 1);
    }
}

// prefix-sum + device-built tile worklist: (e<<16)|m0, e=8 -> shared expert
__global__ void scan_k(const int* __restrict__ counts, int* __restrict__ offsets,
                       int* __restrict__ wl, int* __restrict__ wl_n) {
    if (threadIdx.x == 0) {
        int s = 0;
        for (int e = 0; e < EEXP; e++) { offsets[e] = s; s += counts[e]; }
        offsets[EEXP] = s;
        int n = 0;
        for (int e = 0; e <= EEXP; e++) {
            int Ne = (e == EEXP) ? T_TOK : counts[e];
            for (int m0 = 0; m0 < Ne; m0 += MT) wl[n++] = (e << 16) | m0;
        }
        wl_n[0] = n;   // <= 32
    }
}

__global__ void build_k(const int* __restrict__ topi, const int* __restrict__ offsets,
                        int* __restrict__ cursors, int* __restrict__ rows_token,
                        int* __restrict__ rowof) {
    int t = blockIdx.x * 256 + threadIdx.x;
    if (t >= T_TOK) return;
    for (int k = 0; k < KTOP; k++) {
        int e = topi[2 * t + k];
        int pos = atomicAdd(&cursors[e], 1);
        int r = offsets[e] + pos;
        rows_token[r] = t;
        rowof[2 * t + k] = r;
    }
}

// ---------------- pre-pass: casts & transposes ----------------

__global__ void xcast_k(const float* __restrict__ X, unsigned short* __restrict__ Xb) {
    int i = (blockIdx.x * 256 + threadIdx.x) * 8;
    float4 a = *(const float4*)(X + i);
    float4 b = *(const float4*)(X + i + 4);
    unsigned short o[8] = { f2bf(a.x), f2bf(a.y), f2bf(a.z), f2bf(a.w),
                            f2bf(b.x), f2bf(b.y), f2bf(b.z), f2bf(b.w) };
    *(uint4*)(Xb + i) = *(const uint4*)o;
}

// W [z][K][N] f32 -> Wt [z][N][K] bf16, 128(k) x 64(n) tiles, 4x4 reg transpose
__global__ __launch_bounds__(256) void tcast_k(const float* __restrict__ S,
                                               unsigned short* __restrict__ Dm,
                                               int Kd, int Nn) {
    size_t zoff = (size_t)blockIdx.z * Kd * Nn;
    S += zoff; Dm += zoff;
    int k0 = blockIdx.y * 128, n0 = blockIdx.x * 64;
    __shared__ __align__(16) unsigned short t[64][132];
    int tid = threadIdx.x;
    int nc = (tid & 15) * 4;
    int kq = (tid >> 4) * 4;
#pragma unroll
    for (int j = 0; j < 2; j++) {
        int kb = j * 64 + kq;
        const float* p0 = S + (size_t)(k0 + kb) * Nn + n0 + nc;
        float4 q0 = *(const float4*)(p0);
        float4 q1 = *(const float4*)(p0 + (size_t)Nn);
        float4 q2 = *(const float4*)(p0 + 2 * (size_t)Nn);
        float4 q3 = *(const float4*)(p0 + 3 * (size_t)Nn);
#pragma unroll
        for (int i = 0; i < 4; i++) {
            unsigned int lo = (unsigned int)f2bf((&q0.x)[i]) | ((unsigned int)f2bf((&q1.x)[i]) << 16);
            unsigned int hi = (unsigned int)f2bf((&q2.x)[i]) | ((unsigned int)f2bf((&q3.x)[i]) << 16);
            *(uint2*)&t[nc + i][kb] = make_uint2(lo, hi);
        }
    }
    __syncthreads();
    int n = tid >> 4;
    int c = (tid & 15) * 8;
#pragma unroll
    for (int j = 0; j < 4; j++) {
        int nn = j * 16 + n;
        uint2 a = *(const uint2*)&t[nn][c];
        uint2 b = *(const uint2*)&t[nn][c + 4];
        uint4 v = make_uint4(a.x, a.y, b.x, b.y);
        *(uint4*)(Dm + (size_t)(n0 + nn) * Kd + k0 + c) = v;
    }
}

// ---------------- fused up-projection: H = silu(X@W1) * (X@W3) ----------------
// tile 256(M) x 128(N), BK=64, 512 threads (8 waves, 4m x 2n, per-wave 64x64).
// Double-buffered LDS, single barrier per K-step: stage(next) overlaps compute(cur).
#define NB_UP 22                       // max n-blocks (HDIM/128)
__global__ __launch_bounds__(512) void fused_up(
    const unsigned short* __restrict__ Xb,
    const int* __restrict__ rows_token,
    const int* __restrict__ offsets,
    const unsigned short* __restrict__ W1t,   // [8][H][D] bf16
    const unsigned short* __restrict__ W3t,
    const unsigned short* __restrict__ sw1t,  // [HS][D]
    const unsigned short* __restrict__ sw3t,
    unsigned short* __restrict__ Hg,          // [4096][H]
    unsigned short* __restrict__ Hs,          // [2048][HS]
    const int* __restrict__ wl, const int* __restrict__ wl_n)
{
    int wg = xcd_chunk(blockIdx.x, (NB_UP * NT_MAX) / 8);
    int nb = wg >> 5, it = wg & 31;           // n-column-major: panel-sharers contiguous
    if (it >= wl_n[0]) return;
    int pk = wl[it];
    int z = pk >> 16, m0 = pk & 0xffff;
    bool sh = (z == EEXP);
    int roff, Ne, Nn;
    const unsigned short *w1, *w3;
    unsigned short* Ho;
    if (sh) { roff = 0; Ne = T_TOK; Nn = HSDIM; w1 = sw1t; w3 = sw3t; Ho = Hs; }
    else {
        roff = offsets[z]; Ne = offsets[z + 1] - roff; Nn = HDIM;
        w1 = W1t + (size_t)z * HDIM * DDIM;
        w3 = W3t + (size_t)z * HDIM * DDIM;
        Ho = Hg;
    }
    int n0 = nb * 128;
    if (n0 >= Nn) return;

    __shared__ __align__(16) unsigned short As [2][256 * 64];  // 64 KB
    __shared__ __align__(16) unsigned short B1s[2][128 * 64];  // 32 KB
    __shared__ __align__(16) unsigned short B3s[2][128 * 64];  // 32 KB

    int tid = threadIdx.x, lane = tid & 63, wid = tid >> 6;
    int wrm = wid >> 1, wcn = wid & 1;        // per-wave 64 rows x 64 cols
    int sc = (((tid & 7) ^ ((tid >> 3) & 7)) * 8);   // inverse-swizzled source chunk

    const unsigned short* pA[4];
    const unsigned short *pB1[2], *pB3[2];
#pragma unroll
    for (int j = 0; j < 4; j++) {
        int r = j * 64 + (tid >> 3);
        int gr = m0 + r; if (gr >= Ne) gr = Ne - 1;
        int tok = sh ? gr : rows_token[roff + gr];
        pA[j] = Xb + (size_t)tok * DDIM + sc;
    }
#pragma unroll
    for (int j = 0; j < 2; j++) {
        int r = j * 64 + (tid >> 3);
        pB1[j] = w1 + (size_t)(n0 + r) * DDIM + sc;
        pB3[j] = w3 + (size_t)(n0 + r) * DDIM + sc;
    }

    const f32x4 fz = {0.f, 0.f, 0.f, 0.f};
    f32x4 acc1[4][4], acc3[4][4];
#pragma unroll
    for (int mi = 0; mi < 4; mi++)
#pragma unroll
        for (int nj = 0; nj < 4; nj++) { acc1[mi][nj] = fz; acc3[mi][nj] = fz; }

    int dA = (tid >> 3) * 64 + sc;            // u16 dest pos (linear) per lane base row
    // wave-uniform LDS dest bases (u16): slot (j*512 + wid*64) * 8
#define STAGE(b, koff)                                                      \
    {                                                                       \
        _Pragma("unroll")                                                   \
        for (int j = 0; j < 4; j++)                                         \
            gload16(pA[j] + (koff), &As[b][j * 4096 + wid * 512]);          \
        _Pragma("unroll")                                                   \
        for (int j = 0; j < 2; j++) {                                       \
            gload16(pB1[j] + (koff), &B1s[b][j * 4096 + wid * 512]);        \
            gload16(pB3[j] + (koff), &B3s[b][j * 4096 + wid * 512]);        \
        }                                                                   \
    }
    (void)dA;
    STAGE(0, 0);

    int r16 = lane & 15, h = lane >> 4, sw = (lane & 7) << 4;
#pragma unroll 1
    for (int ks = 0; ks < DDIM / BK; ks++) {
        int cur = ks & 1;
        __syncthreads();                       // implicit vmcnt(0): tile ks landed
        if (ks + 1 < DDIM / BK) STAGE(cur ^ 1, (ks + 1) * BK);
        const unsigned short* Ac = As[cur];
        const unsigned short* B1c = B1s[cur];
        const unsigned short* B3c = B3s[cur];
#pragma unroll
        for (int kk = 0; kk < 2; kk++) {
            int cb = (kk * 64 + h * 16) ^ sw;
            bf16x8 a[4], b1[4], b3[4];
#pragma unroll
            for (int mi = 0; mi < 4; mi++)
                a[mi] = *(const bf16x8*)((const char*)Ac + (wrm * 64 + mi * 16 + r16) * 128 + cb);
#pragma unroll
            for (int nj = 0; nj < 4; nj++) {
                b1[nj] = *(const bf16x8*)((const char*)B1c + (wcn * 64 + nj * 16 + r16) * 128 + cb);
                b3[nj] = *(const bf16x8*)((const char*)B3c + (wcn * 64 + nj * 16 + r16) * 128 + cb);
            }
#pragma unroll
            for (int mi = 0; mi < 4; mi++)
#pragma unroll
                for (int nj = 0; nj < 4; nj++) {
                    acc1[mi][nj] = __builtin_amdgcn_mfma_f32_16x16x32_bf16(a[mi], b1[nj], acc1[mi][nj], 0, 0, 0);
                    acc3[mi][nj] = __builtin_amdgcn_mfma_f32_16x16x32_bf16(a[mi], b3[nj], acc3[mi][nj], 0, 0, 0);
                }
        }
    }
#undef STAGE
#pragma unroll
    for (int mi = 0; mi < 4; mi++) {
#pragma unroll
        for (int nj = 0; nj < 4; nj++) {
            int col = n0 + wcn * 64 + nj * 16 + r16;
#pragma unroll
            for (int j = 0; j < 4; j++) {
                int row = wrm * 64 + mi * 16 + h * 4 + j;
                if (m0 + row < Ne) {
                    float aa = acc1[mi][nj][j], bb = acc3[mi][nj][j];
                    float hv = (aa / (1.f + expf(-aa))) * bb;
                    Ho[(size_t)(roff + m0 + row) * Nn + col] = f2bf(hv);
                }
            }
        }
    }
}

// ---------------- down-projection: Y = H @ W2 ----------------
// tile 256(M) x 128(N), BK=64, 512 threads, double-buffered like fused_up.
#define NB_DN 8                        // DDIM/128
__global__ __launch_bounds__(512) void gemm2(
    const unsigned short* __restrict__ Hg,
    const unsigned short* __restrict__ Hs,
    const unsigned short* __restrict__ W2t,   // [8][D][H] bf16
    const unsigned short* __restrict__ sw2t,  // [D][HS]
    const int* __restrict__ offsets,
    float* __restrict__ Yg,
    float* __restrict__ out,
    const int* __restrict__ wl, const int* __restrict__ wl_n)
{
    int wg = xcd_chunk(blockIdx.x, (NB_DN * NT_MAX) / 8);
    int nb = wg >> 5, it = wg & 31;
    if (it >= wl_n[0]) return;
    int pk = wl[it];
    int z = pk >> 16, m0 = pk & 0xffff;
    bool sh = (z == EEXP);
    int roff, Ne, Kd;
    const unsigned short *Ab, *Bb;
    float* Yo;
    if (sh) { roff = 0; Ne = T_TOK; Kd = HSDIM; Ab = Hs; Bb = sw2t; Yo = out; }
    else {
        roff = offsets[z]; Ne = offsets[z + 1] - roff; Kd = HDIM;
        Ab = Hg + (size_t)roff * HDIM;
        Bb = W2t + (size_t)z * DDIM * HDIM;
        Yo = Yg + (size_t)roff * DDIM;
    }
    int n0 = nb * 128;

    __shared__ __align__(16) unsigned short As[2][256 * 64];   // 64 KB
    __shared__ __align__(16) unsigned short Bs[2][128 * 64];   // 32 KB

    int tid = threadIdx.x, lane = tid & 63, wid = tid >> 6;
    int wrm = wid >> 1, wcn = wid & 1;
    int sc = (((tid & 7) ^ ((tid >> 3) & 7)) * 8);

    const unsigned short* pA[4];
    const unsigned short* pB[2];
#pragma unroll
    for (int j = 0; j < 4; j++) {
        int r = j * 64 + (tid >> 3);
        int gr = m0 + r; if (gr >= Ne) gr = Ne - 1;
        pA[j] = Ab + (size_t)gr * Kd + sc;
    }
#pragma unroll
    for (int j = 0; j < 2; j++) {
        int r = j * 64 + (tid >> 3);
        pB[j] = Bb + (size_t)(n0 + r) * Kd + sc;
    }

    const f32x4 fz = {0.f, 0.f, 0.f, 0.f};
    f32x4 acc[4][4];
#pragma unroll
    for (int mi = 0; mi < 4; mi++)
#pragma unroll
        for (int nj = 0; nj < 4; nj++) acc[mi][nj] = fz;

#define STAGE2(b, koff)                                                     \
    {                                                                       \
        _Pragma("unroll")                                                   \
        for (int j = 0; j < 4; j++)                                         \
            gload16(pA[j] + (koff), &As[b][j * 4096 + wid * 512]);          \
        _Pragma("unroll")                                                   \
        for (int j = 0; j < 2; j++)                                         \
            gload16(pB[j] + (koff), &Bs[b][j * 4096 + wid * 512]);          \
    }
    STAGE2(0, 0);

    int nks = Kd / BK;
    int r16 = lane & 15, h = lane >> 4, sw = (lane & 7) << 4;
#pragma unroll 1
    for (int ks = 0; ks < nks; ks++) {
        int cur = ks & 1;
        __syncthreads();
        if (ks + 1 < nks) STAGE2(cur ^ 1, (ks + 1) * BK);
        const unsigned short* Ac = As[cur];
        const unsigned short* Bc = Bs[cur];
#pragma unroll
        for (int kk = 0; kk < 2; kk++) {
            int cb = (kk * 64 + h * 16) ^ sw;
            bf16x8 a[4], b[4];
#pragma unroll
            for (int mi = 0; mi < 4; mi++)
                a[mi] = *(const bf16x8*)((const char*)Ac + (wrm * 64 + mi * 16 + r16) * 128 + cb);
#pragma unroll
            for (int nj = 0; nj < 4; nj++)
                b[nj] = *(const bf16x8*)((const char*)Bc + (wcn * 64 + nj * 16 + r16) * 128 + cb);
#pragma unroll
            for (int mi = 0; mi < 4; mi++)
#pragma unroll
                for (int nj = 0; nj < 4; nj++)
                    acc[mi][nj] = __builtin_amdgcn_mfma_f32_16x16x32_bf16(a[mi], b[nj], acc[mi][nj], 0, 0, 0);
        }
    }
#undef STAGE2
#pragma unroll
    for (int mi = 0; mi < 4; mi++) {
#pragma unroll
        for (int nj = 0; nj < 4; nj++) {
            int col = n0 + wcn * 64 + nj * 16 + r16;
#pragma unroll
            for (int j = 0; j < 4; j++) {
                int row = wrm * 64 + mi * 16 + h * 4 + j;
                if (m0 + row < Ne)
                    Yo[(size_t)(m0 + row) * DDIM + col] = acc[mi][nj][j];
            }
        }
    }
}

// ---------------- final combine ----------------
__global__ void combine_k(float* __restrict__ out, const float* __restrict__ Yg,
                          const int* __restrict__ rowof, const float* __restrict__ topw) {
    int idx = blockIdx.x * 256 + threadIdx.x;
    int t = idx >> 8;
    int dq = (idx & 255) << 2;
    int r0 = rowof[2 * t], r1 = rowof[2 * t + 1];
    float g0 = topw[2 * t], g1 = topw[2 * t + 1];
    float* op = out + (size_t)t * DDIM + dq;
    float4 o = *(float4*)op;
    float4 a = *(const float4*)(Yg + (size_t)r0 * DDIM + dq);
    float4 b = *(const float4*)(Yg + (size_t)r1 * DDIM + dq);
    o.x += g0 * a.x + g1 * b.x;
    o.y += g0 * a.y + g1 * b.y;
    o.z += g0 * a.z + g1 * b.z;
    o.w += g0 * a.w + g1 * b.w;
    *(float4*)op = o;
}

// ---------------- launch ----------------
extern "C" void kernel_launch(void* const* d_in, const int* in_sizes, int n_in,
                              void* d_out, int out_size, void* d_ws, size_t ws_size,
                              hipStream_t stream) {
    const float* x   = (const float*)d_in[0];
    const float* gw  = (const float*)d_in[1];
    const float* w1  = (const float*)d_in[2];
    const float* w3  = (const float*)d_in[3];
    const float* w2  = (const float*)d_in[4];
    const float* sw1 = (const float*)d_in[5];
    const float* sw3 = (const float*)d_in[6];
    const float* sw2 = (const float*)d_in[7];
    float* out = (float*)d_out;
    char* ws = (char*)d_ws;

    const size_t MB = 1048576;
    int*   counts     = (int*)(ws);
    int*   offsets    = (int*)(ws + 64);
    int*   cursors    = (int*)(ws + 128);
    int*   wl_n       = (int*)(ws + 192);
    int*   wl         = (int*)(ws + 256);
    int*   topi       = (int*)(ws + 512);
    float* topw       = (float*)(ws + 16896);
    int*   rows_token = (int*)(ws + 33280);
    int*   rowof      = (int*)(ws + 49664);
    unsigned short* Xb   = (unsigned short*)(ws + 1 * MB);    // 4 MB
    unsigned short* sw1t = (unsigned short*)(ws + 6 * MB);    // 3 MB
    unsigned short* sw3t = (unsigned short*)(ws + 9 * MB);    // 3 MB
    unsigned short* sw2t = (unsigned short*)(ws + 12 * MB);   // 3 MB
    unsigned short* Hg   = (unsigned short*)(ws + 16 * MB);   // 22 MB
    float*          Yg   = (float*)(ws + 40 * MB);            // 16 MB
    unsigned short* Hs   = (unsigned short*)(ws + 56 * MB);   // 6 MB
    unsigned short* W1t  = (unsigned short*)(ws + 64 * MB);   // 44 MB
    unsigned short* W3t  = (unsigned short*)(ws + 108 * MB);  // 44 MB (ends 152 MB)
    unsigned short* W2t  = W1t;  // aliased: converted after fused_up consumes W1t

    // routing
    init_k<<<1, 64, 0, stream>>>(counts, cursors);
    gate_k<<<T_TOK / 4, 256, 0, stream>>>(x, gw, topi, topw, counts);
    scan_k<<<1, 64, 0, stream>>>(counts, offsets, wl, wl_n);
    build_k<<<T_TOK / 256, 256, 0, stream>>>(topi, offsets, cursors, rows_token, rowof);

    // pre-pass: bf16 casts + weight transposes
    xcast_k<<<(T_TOK * DDIM / 8) / 256, 256, 0, stream>>>(x, Xb);
    tcast_k<<<dim3(HDIM / 64, DDIM / 128, EEXP), 256, 0, stream>>>(w1, W1t, DDIM, HDIM);
    tcast_k<<<dim3(HDIM / 64, DDIM / 128, EEXP), 256, 0, stream>>>(w3, W3t, DDIM, HDIM);
    tcast_k<<<dim3(HSDIM / 64, DDIM / 128, 1), 256, 0, stream>>>(sw1, sw1t, DDIM, HSDIM);
    tcast_k<<<dim3(HSDIM / 64, DDIM / 128, 1), 256, 0, stream>>>(sw3, sw3t, DDIM, HSDIM);
    tcast_k<<<dim3(DDIM / 64, HSDIM / 128, 1), 256, 0, stream>>>(sw2, sw2t, HSDIM, DDIM);

    // up-projection (worklist covers routed + shared tiles)
    fused_up<<<NB_UP * NT_MAX, 512, 0, stream>>>(
        Xb, rows_token, offsets, W1t, W3t, sw1t, sw3t, Hg, Hs, wl, wl_n);

    // W2 transpose (into aliased region, after fused_up is done with W1t)
    tcast_k<<<dim3(DDIM / 64, HDIM / 128, EEXP), 256, 0, stream>>>(w2, W2t, HDIM, DDIM);

    // down-projection (routed -> Yg, shared -> out direct)
    gemm2<<<NB_DN * NT_MAX, 512, 0, stream>>>(
        Hg, Hs, W2t, sw2t, offsets, Yg, out, wl, wl_n);

    // out = shared + g0*y0 + g1*y1
    combine_k<<<(T_TOK * DDIM / 4) / 256, 256, 0, stream>>>(out, Yg, rowof, topw);
}

// Round 5
// 315.824 us; speedup vs baseline: 1.1266x; 1.1266x over previous
//
#include <hip/hip_runtime.h>
#include <hip/hip_bf16.h>

// Problem constants
#define T_TOK 2048      // B*S
#define DDIM  1024
#define EEXP  8
#define KTOP  2
#define HDIM  2816
#define HSDIM 1536
#define BK    64
#define MT    128       // GEMM m-tile
#define NT    56        // worklist capacity: sum ceil(Ne/128) <= 40 routed + 16 shared

typedef float f32x4 __attribute__((ext_vector_type(4)));
typedef short bf16x8 __attribute__((ext_vector_type(8)));

__device__ __forceinline__ unsigned short f2bf(float f) {
    __hip_bfloat16 h = __float2bfloat16(f);
    return __builtin_bit_cast(unsigned short, h);
}

// async global->LDS, 16B per lane; LDS dest = wave-uniform base + lane*16
__device__ __forceinline__ void gload16(const unsigned short* g, unsigned short* l) {
    __builtin_amdgcn_global_load_lds(
        (const __attribute__((address_space(1))) unsigned int*)g,
        (__attribute__((address_space(3))) unsigned int*)l, 16, 0, 0);
}

// bijective chunked XCD remap (m204): hw block i -> XCD i%8; each XCD gets a
// contiguous LOGICAL range so weight-panel-sharing blocks co-reside on one L2.
__device__ __forceinline__ int xcd_chunk(int i, int nwg8) {
    return (i & 7) * nwg8 + (i >> 3);   // nwg8 = nwg/8, nwg % 8 == 0
}

// ---------------- small routing kernels ----------------

__global__ void init_k(int* counts, int* cursors) {
    if (threadIdx.x < EEXP) { counts[threadIdx.x] = 0; cursors[threadIdx.x] = 0; }
}

__global__ void gate_k(const float* __restrict__ X, const float* __restrict__ GW,
                       int* __restrict__ topi, float* __restrict__ topw,
                       int* __restrict__ counts) {
    int lane = threadIdx.x & 63;
    int t = blockIdx.x * 4 + (threadIdx.x >> 6);
    int e  = lane >> 3;
    int c8 = lane & 7;
    const float* xr = X + (size_t)t * DDIM;
    const float* gr = GW + (size_t)e * DDIM;
    float acc = 0.f;
#pragma unroll 8
    for (int j = 0; j < 32; j++) {
        int d = (c8 + 8 * j) * 4;
        float4 xv = *(const float4*)(xr + d);
        float4 gv = *(const float4*)(gr + d);
        acc += xv.x * gv.x + xv.y * gv.y + xv.z * gv.z + xv.w * gv.w;
    }
    acc += __shfl_xor(acc, 1);
    acc += __shfl_xor(acc, 2);
    acc += __shfl_xor(acc, 4);
    float p[8];
#pragma unroll
    for (int q = 0; q < 8; q++) p[q] = __shfl(acc, q * 8);
    float mx = p[0];
#pragma unroll
    for (int q = 1; q < 8; q++) mx = fmaxf(mx, p[q]);
    float s = 0.f;
#pragma unroll
    for (int q = 0; q < 8; q++) { p[q] = expf(p[q] - mx); s += p[q]; }
    float inv = 1.f / s;
#pragma unroll
    for (int q = 0; q < 8; q++) p[q] *= inv;
    float v1 = -1.f; int i1 = 0;
#pragma unroll
    for (int q = 0; q < 8; q++) { if (p[q] > v1) { v1 = p[q]; i1 = q; } }
    float v2 = -1.f; int i2 = 0;
#pragma unroll
    for (int q = 0; q < 8; q++) { if (q != i1 && p[q] > v2) { v2 = p[q]; i2 = q; } }
    if (lane == 0) {
        topi[2 * t] = i1; topi[2 * t + 1] = i2;
        topw[2 * t] = v1; topw[2 * t + 1] = v2;
        atomicAdd(&counts[i1], 1);
        atomicAdd(&counts[i2], 1);
    }
}

// prefix-sum + device-built tile worklist: (e<<16)|m0, e=8 -> shared expert
__global__ void scan_k(const int* __restrict__ counts, int* __restrict__ offsets,
                       int* __restrict__ wl, int* __restrict__ wl_n) {
    if (threadIdx.x == 0) {
        int s = 0;
        for (int e = 0; e < EEXP; e++) { offsets[e] = s; s += counts[e]; }
        offsets[EEXP] = s;
        int n = 0;
        for (int e = 0; e <= EEXP; e++) {
            int Ne = (e == EEXP) ? T_TOK : counts[e];
            for (int m0 = 0; m0 < Ne; m0 += MT) wl[n++] = (e << 16) | m0;
        }
        wl_n[0] = n;   // <= 56
    }
}

__global__ void build_k(const int* __restrict__ topi, const int* __restrict__ offsets,
                        int* __restrict__ cursors, int* __restrict__ rows_token,
                        int* __restrict__ rowof) {
    int t = blockIdx.x * 256 + threadIdx.x;
    if (t >= T_TOK) return;
    for (int k = 0; k < KTOP; k++) {
        int e = topi[2 * t + k];
        int pos = atomicAdd(&cursors[e], 1);
        int r = offsets[e] + pos;
        rows_token[r] = t;
        rowof[2 * t + k] = r;
    }
}

// ---------------- consolidated pre-pass ----------------
// job table (compile-time):
//  [0,1024)       xcast: X f32 -> Xb bf16
//  [1024,3840)    w1  -> W1t   (z,kb,nb)
//  [3840,6656)    w3  -> W3t
//  [6656,6848)    sw1 -> sw1t
//  [6848,7040)    sw3 -> sw3t
//  [7040,7232)    sw2 -> sw2t
#define PREP_GRID 7232

__device__ __forceinline__ void tcast_tile(const float* __restrict__ S,
                                           unsigned short* __restrict__ Dm,
                                           int Kd, int Nn, int k0, int n0,
                                           unsigned short (*t)[132]) {
    int tid = threadIdx.x;
    int nc = (tid & 15) * 4;
    int kq = (tid >> 4) * 4;
#pragma unroll
    for (int j = 0; j < 2; j++) {
        int kb = j * 64 + kq;
        const float* p0 = S + (size_t)(k0 + kb) * Nn + n0 + nc;
        float4 q0 = *(const float4*)(p0);
        float4 q1 = *(const float4*)(p0 + (size_t)Nn);
        float4 q2 = *(const float4*)(p0 + 2 * (size_t)Nn);
        float4 q3 = *(const float4*)(p0 + 3 * (size_t)Nn);
#pragma unroll
        for (int i = 0; i < 4; i++) {
            unsigned int lo = (unsigned int)f2bf((&q0.x)[i]) | ((unsigned int)f2bf((&q1.x)[i]) << 16);
            unsigned int hi = (unsigned int)f2bf((&q2.x)[i]) | ((unsigned int)f2bf((&q3.x)[i]) << 16);
            *(uint2*)&t[nc + i][kb] = make_uint2(lo, hi);
        }
    }
    __syncthreads();
    int n = tid >> 4;
    int c = (tid & 15) * 8;
#pragma unroll
    for (int j = 0; j < 4; j++) {
        int nn = j * 16 + n;
        uint2 a = *(const uint2*)&t[nn][c];
        uint2 b = *(const uint2*)&t[nn][c + 4];
        uint4 v = make_uint4(a.x, a.y, b.x, b.y);
        *(uint4*)(Dm + (size_t)(n0 + nn) * Kd + k0 + c) = v;
    }
}

__global__ __launch_bounds__(256) void prep_k(
    const float* __restrict__ x,
    const float* __restrict__ w1, const float* __restrict__ w3,
    const float* __restrict__ sw1, const float* __restrict__ sw3,
    const float* __restrict__ sw2,
    unsigned short* __restrict__ Xb,
    unsigned short* __restrict__ W1t, unsigned short* __restrict__ W3t,
    unsigned short* __restrict__ sw1t, unsigned short* __restrict__ sw3t,
    unsigned short* __restrict__ sw2t)
{
    __shared__ __align__(16) unsigned short t[64][132];
    int b = blockIdx.x;
    if (b < 1024) {
        int i = b * 2048 + threadIdx.x * 8;
        float4 a = *(const float4*)(x + i);
        float4 c = *(const float4*)(x + i + 4);
        unsigned short o[8] = { f2bf(a.x), f2bf(a.y), f2bf(a.z), f2bf(a.w),
                                f2bf(c.x), f2bf(c.y), f2bf(c.z), f2bf(c.w) };
        *(uint4*)(Xb + i) = *(const uint4*)o;
        return;
    }
    const float* S; unsigned short* D; int Kd, Nn, k0, n0;
    if (b < 3840) {
        int idx = b - 1024, z = idx / 352, r = idx % 352;
        Kd = DDIM; Nn = HDIM;
        S = w1 + (size_t)z * DDIM * HDIM; D = W1t + (size_t)z * DDIM * HDIM;
        k0 = (r / 44) * 128; n0 = (r % 44) * 64;
    } else if (b < 6656) {
        int idx = b - 3840, z = idx / 352, r = idx % 352;
        Kd = DDIM; Nn = HDIM;
        S = w3 + (size_t)z * DDIM * HDIM; D = W3t + (size_t)z * DDIM * HDIM;
        k0 = (r / 44) * 128; n0 = (r % 44) * 64;
    } else if (b < 6848) {
        int idx = b - 6656;
        Kd = DDIM; Nn = HSDIM; S = sw1; D = sw1t;
        k0 = (idx / 24) * 128; n0 = (idx % 24) * 64;
    } else if (b < 7040) {
        int idx = b - 6848;
        Kd = DDIM; Nn = HSDIM; S = sw3; D = sw3t;
        k0 = (idx / 24) * 128; n0 = (idx % 24) * 64;
    } else {
        int idx = b - 7040;
        Kd = HSDIM; Nn = DDIM; S = sw2; D = sw2t;
        k0 = (idx / 16) * 128; n0 = (idx % 16) * 64;
    }
    tcast_tile(S, D, Kd, Nn, k0, n0, t);
}

// W [z][K][N] f32 -> Wt [z][N][K] bf16 (used for W2 after aliasing window)
__global__ __launch_bounds__(256) void tcast_k(const float* __restrict__ S,
                                               unsigned short* __restrict__ Dm,
                                               int Kd, int Nn) {
    __shared__ __align__(16) unsigned short t[64][132];
    size_t zoff = (size_t)blockIdx.z * Kd * Nn;
    tcast_tile(S + zoff, Dm + zoff, Kd, Nn, blockIdx.y * 128, blockIdx.x * 64, t);
}

// ---------------- fused up-projection: H = silu(X@W1) * (X@W3) ----------------
// tile 128(M) x 128(N), BK=64, 4 waves 2x2, per-wave 64x64 dual-accumulated.
// grid: 22 n-blocks x 56 worklist items, XCD-chunked n-major.
__global__ __launch_bounds__(256, 2) void fused_up(
    const unsigned short* __restrict__ Xb,
    const int* __restrict__ rows_token,
    const int* __restrict__ offsets,
    const unsigned short* __restrict__ W1t,   // [8][H][D] bf16
    const unsigned short* __restrict__ W3t,
    const unsigned short* __restrict__ sw1t,  // [HS][D]
    const unsigned short* __restrict__ sw3t,
    unsigned short* __restrict__ Hg,          // [4096][H]
    unsigned short* __restrict__ Hs,          // [2048][HS]
    const int* __restrict__ wl, const int* __restrict__ wl_n)
{
    int wg = xcd_chunk(blockIdx.x, (22 * NT) / 8);
    int nb = wg / NT, it = wg % NT;           // n-major: panel-sharers contiguous
    if (it >= wl_n[0]) return;
    int pk = wl[it];
    int z = pk >> 16, m0 = pk & 0xffff;
    bool sh = (z == EEXP);
    int roff, Ne, Nn;
    const unsigned short *w1, *w3;
    unsigned short* Ho;
    if (sh) { roff = 0; Ne = T_TOK; Nn = HSDIM; w1 = sw1t; w3 = sw3t; Ho = Hs; }
    else {
        roff = offsets[z]; Ne = offsets[z + 1] - roff; Nn = HDIM;
        w1 = W1t + (size_t)z * HDIM * DDIM;
        w3 = W3t + (size_t)z * HDIM * DDIM;
        Ho = Hg;
    }
    int n0 = nb * 128;
    if (n0 >= Nn) return;

    __shared__ __align__(16) unsigned short As [128 * 64];
    __shared__ __align__(16) unsigned short B1s[128 * 64];
    __shared__ __align__(16) unsigned short B3s[128 * 64];

    int tid = threadIdx.x, lane = tid & 63, wid = tid >> 6;
    int wr = wid >> 1, wc = wid & 1;          // per-wave 64 rows x 64 cols
    int sc = ((lane & 7) ^ (lane >> 3)) * 8;  // inverse-swizzled source chunk

    const unsigned short* pA[4];
    const unsigned short *pB1[4], *pB3[4];
#pragma unroll
    for (int j = 0; j < 4; j++) {
        int lr = (wid * 4 + j) * 8 + (lane >> 3);
        int gr = m0 + lr; if (gr >= Ne) gr = Ne - 1;
        int tok = sh ? gr : rows_token[roff + gr];
        pA[j]  = Xb + (size_t)tok * DDIM + sc;
        pB1[j] = w1 + (size_t)(n0 + lr) * DDIM + sc;
        pB3[j] = w3 + (size_t)(n0 + lr) * DDIM + sc;
    }

    const f32x4 fz = {0.f, 0.f, 0.f, 0.f};
    f32x4 acc1[4][4], acc3[4][4];
#pragma unroll
    for (int mi = 0; mi < 4; mi++)
#pragma unroll
        for (int nj = 0; nj < 4; nj++) { acc1[mi][nj] = fz; acc3[mi][nj] = fz; }

#pragma unroll 1
    for (int ks = 0; ks < DDIM / BK; ks++) {
        __syncthreads();
#pragma unroll
        for (int j = 0; j < 4; j++) gload16(pA[j],  As  + (wid * 4 + j) * 512);
#pragma unroll
        for (int j = 0; j < 4; j++) gload16(pB1[j], B1s + (wid * 4 + j) * 512);
#pragma unroll
        for (int j = 0; j < 4; j++) gload16(pB3[j], B3s + (wid * 4 + j) * 512);
#pragma unroll
        for (int j = 0; j < 4; j++) { pA[j] += BK; pB1[j] += BK; pB3[j] += BK; }
        __syncthreads();
        int r = lane & 15, h = lane >> 4, sw = (lane & 7) << 4;
#pragma unroll
        for (int kk = 0; kk < 2; kk++) {
            int cb = (kk * 64 + h * 16) ^ sw;
            bf16x8 a[4], b1[4], b3[4];
#pragma unroll
            for (int mi = 0; mi < 4; mi++)
                a[mi] = *(const bf16x8*)((const char*)As + (wr * 64 + mi * 16 + r) * 128 + cb);
#pragma unroll
            for (int nj = 0; nj < 4; nj++) {
                b1[nj] = *(const bf16x8*)((const char*)B1s + (wc * 64 + nj * 16 + r) * 128 + cb);
                b3[nj] = *(const bf16x8*)((const char*)B3s + (wc * 64 + nj * 16 + r) * 128 + cb);
            }
#pragma unroll
            for (int mi = 0; mi < 4; mi++)
#pragma unroll
                for (int nj = 0; nj < 4; nj++) {
                    acc1[mi][nj] = __builtin_amdgcn_mfma_f32_16x16x32_bf16(a[mi], b1[nj], acc1[mi][nj], 0, 0, 0);
                    acc3[mi][nj] = __builtin_amdgcn_mfma_f32_16x16x32_bf16(a[mi], b3[nj], acc3[mi][nj], 0, 0, 0);
                }
        }
    }
    int r = lane & 15, h = lane >> 4;
#pragma unroll
    for (int mi = 0; mi < 4; mi++) {
#pragma unroll
        for (int nj = 0; nj < 4; nj++) {
            int col = n0 + wc * 64 + nj * 16 + r;
#pragma unroll
            for (int j = 0; j < 4; j++) {
                int row = wr * 64 + mi * 16 + h * 4 + j;
                if (m0 + row < Ne) {
                    float aa = acc1[mi][nj][j], bb = acc3[mi][nj][j];
                    float hv = (aa / (1.f + expf(-aa))) * bb;
                    Ho[(size_t)(roff + m0 + row) * Nn + col] = f2bf(hv);
                }
            }
        }
    }
}

// ---------------- down-projection: Y = H @ W2 ----------------
// tile 128(M) x 128(N), BK=64, 4 waves 2x2, per-wave 64x64; XCD-chunked n-major.
__global__ __launch_bounds__(256) void gemm2(
    const unsigned short* __restrict__ Hg,
    const unsigned short* __restrict__ Hs,
    const unsigned short* __restrict__ W2t,   // [8][D][H] bf16
    const unsigned short* __restrict__ sw2t,  // [D][HS]
    const int* __restrict__ offsets,
    float* __restrict__ Yg,
    float* __restrict__ out,
    const int* __restrict__ wl, const int* __restrict__ wl_n)
{
    int wg = xcd_chunk(blockIdx.x, (8 * NT) / 8);
    int nb = wg / NT, it = wg % NT;
    if (it >= wl_n[0]) return;
    int pk = wl[it];
    int z = pk >> 16, m0 = pk & 0xffff;
    bool sh = (z == EEXP);
    int roff, Ne, Kd;
    const unsigned short *Ab, *Bb;
    float* Yo;
    if (sh) { roff = 0; Ne = T_TOK; Kd = HSDIM; Ab = Hs; Bb = sw2t; Yo = out; }
    else {
        roff = offsets[z]; Ne = offsets[z + 1] - roff; Kd = HDIM;
        Ab = Hg + (size_t)roff * HDIM;
        Bb = W2t + (size_t)z * DDIM * HDIM;
        Yo = Yg + (size_t)roff * DDIM;
    }
    int n0 = nb * 128;

    __shared__ __align__(16) unsigned short As[128 * 64];
    __shared__ __align__(16) unsigned short Bs[128 * 64];

    int tid = threadIdx.x, lane = tid & 63, wid = tid >> 6;
    int wr = wid >> 1, wc = wid & 1;
    int sc = ((lane & 7) ^ (lane >> 3)) * 8;

    const unsigned short* pA[4];
    const unsigned short* pB[4];
#pragma unroll
    for (int j = 0; j < 4; j++) {
        int lr = (wid * 4 + j) * 8 + (lane >> 3);
        int gr = m0 + lr; if (gr >= Ne) gr = Ne - 1;
        pA[j] = Ab + (size_t)gr * Kd + sc;
        pB[j] = Bb + (size_t)(n0 + lr) * Kd + sc;
    }

    const f32x4 fz = {0.f, 0.f, 0.f, 0.f};
    f32x4 acc[4][4];
#pragma unroll
    for (int mi = 0; mi < 4; mi++)
#pragma unroll
        for (int nj = 0; nj < 4; nj++) acc[mi][nj] = fz;

    int nks = Kd / BK;
#pragma unroll 1
    for (int ks = 0; ks < nks; ks++) {
        __syncthreads();
#pragma unroll
        for (int j = 0; j < 4; j++) gload16(pA[j], As + (wid * 4 + j) * 512);
#pragma unroll
        for (int j = 0; j < 4; j++) gload16(pB[j], Bs + (wid * 4 + j) * 512);
#pragma unroll
        for (int j = 0; j < 4; j++) { pA[j] += BK; pB[j] += BK; }
        __syncthreads();
        int r = lane & 15, h = lane >> 4, sw = (lane & 7) << 4;
#pragma unroll
        for (int kk = 0; kk < 2; kk++) {
            int cb = (kk * 64 + h * 16) ^ sw;
            bf16x8 a[4], b[4];
#pragma unroll
            for (int mi = 0; mi < 4; mi++)
                a[mi] = *(const bf16x8*)((const char*)As + (wr * 64 + mi * 16 + r) * 128 + cb);
#pragma unroll
            for (int nj = 0; nj < 4; nj++)
                b[nj] = *(const bf16x8*)((const char*)Bs + (wc * 64 + nj * 16 + r) * 128 + cb);
#pragma unroll
            for (int mi = 0; mi < 4; mi++)
#pragma unroll
                for (int nj = 0; nj < 4; nj++)
                    acc[mi][nj] = __builtin_amdgcn_mfma_f32_16x16x32_bf16(a[mi], b[nj], acc[mi][nj], 0, 0, 0);
        }
    }
    int r = lane & 15, h = lane >> 4;
#pragma unroll
    for (int mi = 0; mi < 4; mi++) {
#pragma unroll
        for (int nj = 0; nj < 4; nj++) {
            int col = n0 + wc * 64 + nj * 16 + r;
#pragma unroll
            for (int j = 0; j < 4; j++) {
                int row = wr * 64 + mi * 16 + h * 4 + j;
                if (m0 + row < Ne)
                    Yo[(size_t)(m0 + row) * DDIM + col] = acc[mi][nj][j];
            }
        }
    }
}

// ---------------- final combine ----------------
__global__ void combine_k(float* __restrict__ out, const float* __restrict__ Yg,
                          const int* __restrict__ rowof, const float* __restrict__ topw) {
    int idx = blockIdx.x * 256 + threadIdx.x;
    int t = idx >> 8;
    int dq = (idx & 255) << 2;
    int r0 = rowof[2 * t], r1 = rowof[2 * t + 1];
    float g0 = topw[2 * t], g1 = topw[2 * t + 1];
    float* op = out + (size_t)t * DDIM + dq;
    float4 o = *(float4*)op;
    float4 a = *(const float4*)(Yg + (size_t)r0 * DDIM + dq);
    float4 b = *(const float4*)(Yg + (size_t)r1 * DDIM + dq);
    o.x += g0 * a.x + g1 * b.x;
    o.y += g0 * a.y + g1 * b.y;
    o.z += g0 * a.z + g1 * b.z;
    o.w += g0 * a.w + g1 * b.w;
    *(float4*)op = o;
}

// ---------------- launch ----------------
extern "C" void kernel_launch(void* const* d_in, const int* in_sizes, int n_in,
                              void* d_out, int out_size, void* d_ws, size_t ws_size,
                              hipStream_t stream) {
    const float* x   = (const float*)d_in[0];
    const float* gw  = (const float*)d_in[1];
    const float* w1  = (const float*)d_in[2];
    const float* w3  = (const float*)d_in[3];
    const float* w2  = (const float*)d_in[4];
    const float* sw1 = (const float*)d_in[5];
    const float* sw3 = (const float*)d_in[6];
    const float* sw2 = (const float*)d_in[7];
    float* out = (float*)d_out;
    char* ws = (char*)d_ws;

    const size_t MB = 1048576;
    int*   counts     = (int*)(ws);
    int*   offsets    = (int*)(ws + 64);
    int*   cursors    = (int*)(ws + 128);
    int*   wl_n       = (int*)(ws + 192);
    int*   wl         = (int*)(ws + 256);
    int*   topi       = (int*)(ws + 512);
    float* topw       = (float*)(ws + 16896);
    int*   rows_token = (int*)(ws + 33280);
    int*   rowof      = (int*)(ws + 49664);
    unsigned short* Xb   = (unsigned short*)(ws + 1 * MB);    // 4 MB
    unsigned short* sw1t = (unsigned short*)(ws + 6 * MB);    // 3 MB
    unsigned short* sw3t = (unsigned short*)(ws + 9 * MB);    // 3 MB
    unsigned short* sw2t = (unsigned short*)(ws + 12 * MB);   // 3 MB
    unsigned short* Hg   = (unsigned short*)(ws + 16 * MB);   // 22 MB
    float*          Yg   = (float*)(ws + 40 * MB);            // 16 MB
    unsigned short* Hs   = (unsigned short*)(ws + 56 * MB);   // 6 MB
    unsigned short* W1t  = (unsigned short*)(ws + 64 * MB);   // 44 MB
    unsigned short* W3t  = (unsigned short*)(ws + 108 * MB);  // 44 MB (ends 152 MB)
    unsigned short* W2t  = W1t;  // aliased: converted after fused_up consumes W1t

    // routing
    init_k<<<1, 64, 0, stream>>>(counts, cursors);
    gate_k<<<T_TOK / 4, 256, 0, stream>>>(x, gw, topi, topw, counts);
    scan_k<<<1, 64, 0, stream>>>(counts, offsets, wl, wl_n);
    build_k<<<T_TOK / 256, 256, 0, stream>>>(topi, offsets, cursors, rows_token, rowof);

    // consolidated pre-pass: xcast + all transposes except w2
    prep_k<<<PREP_GRID, 256, 0, stream>>>(x, w1, w3, sw1, sw3, sw2,
                                          Xb, W1t, W3t, sw1t, sw3t, sw2t);

    // up-projection (worklist covers routed + shared tiles)
    fused_up<<<22 * NT, 256, 0, stream>>>(
        Xb, rows_token, offsets, W1t, W3t, sw1t, sw3t, Hg, Hs, wl, wl_n);

    // W2 transpose (into aliased region, after fused_up is done with W1t)
    tcast_k<<<dim3(DDIM / 64, HDIM / 128, EEXP), 256, 0, stream>>>(w2, W2t, HDIM, DDIM);

    // down-projection (routed -> Yg, shared -> out direct)
    gemm2<<<8 * NT, 256, 0, stream>>>(
        Hg, Hs, W2t, sw2t, offsets, Yg, out, wl, wl_n);

    // out = shared + g0*y0 + g1*y1
    combine_k<<<(T_TOK * DDIM / 4) / 256, 256, 0, stream>>>(out, Yg, rowof, topw);
}

// Round 6
// 294.225 us; speedup vs baseline: 1.2093x; 1.0734x over previous
//
#include <hip/hip_runtime.h>
#include <hip/hip_bf16.h>

// Problem constants
#define T_TOK 2048      // B*S
#define DDIM  1024
#define EEXP  8
#define KTOP  2
#define HDIM  2816
#define HSDIM 1536
#define BK    64
#define MT    128       // GEMM m-tile
#define NB_UP 22        // HDIM/128
#define NB_SH 12        // HSDIM/128
#define NB_DN 8         // DDIM/128
#define GRID_UP 1072    // max live: 12*56 + 10*40
#define GRID_DN 448     // 8*56

typedef float f32x4 __attribute__((ext_vector_type(4)));
typedef short bf16x8 __attribute__((ext_vector_type(8)));

__device__ __forceinline__ unsigned short f2bf(float f) {
    __hip_bfloat16 h = __float2bfloat16(f);
    return __builtin_bit_cast(unsigned short, h);
}

// async global->LDS, 16B per lane; LDS dest = wave-uniform base + lane*16
__device__ __forceinline__ void gload16(const unsigned short* g, unsigned short* l) {
    __builtin_amdgcn_global_load_lds(
        (const __attribute__((address_space(1))) unsigned int*)g,
        (__attribute__((address_space(3))) unsigned int*)l, 16, 0, 0);
}

// Bijective chunked XCD remap over a RUNTIME live count (m204 general form).
// hw block i -> xcd = i%8 (MI355X round-robin); each XCD owns a contiguous
// logical range of the live [0,n) space. Returns -1 for dead padding blocks.
__device__ __forceinline__ int xcd_live_map(int i, int n) {
    int q = n >> 3, r = n & 7;
    int xcd = i & 7, loc = i >> 3;
    int cap = q + (xcd < r ? 1 : 0);
    if (loc >= cap) return -1;
    return (xcd < r ? xcd * (q + 1) : r * (q + 1) + (xcd - r) * q) + loc;
}

// ---------------- small routing kernels ----------------

__global__ void init_k(int* counts, int* cursors) {
    if (threadIdx.x < EEXP) { counts[threadIdx.x] = 0; cursors[threadIdx.x] = 0; }
}

__global__ void gate_k(const float* __restrict__ X, const float* __restrict__ GW,
                       int* __restrict__ topi, float* __restrict__ topw,
                       int* __restrict__ counts) {
    int lane = threadIdx.x & 63;
    int t = blockIdx.x * 4 + (threadIdx.x >> 6);
    int e  = lane >> 3;
    int c8 = lane & 7;
    const float* xr = X + (size_t)t * DDIM;
    const float* gr = GW + (size_t)e * DDIM;
    float acc = 0.f;
#pragma unroll 8
    for (int j = 0; j < 32; j++) {
        int d = (c8 + 8 * j) * 4;
        float4 xv = *(const float4*)(xr + d);
        float4 gv = *(const float4*)(gr + d);
        acc += xv.x * gv.x + xv.y * gv.y + xv.z * gv.z + xv.w * gv.w;
    }
    acc += __shfl_xor(acc, 1);
    acc += __shfl_xor(acc, 2);
    acc += __shfl_xor(acc, 4);
    float p[8];
#pragma unroll
    for (int q = 0; q < 8; q++) p[q] = __shfl(acc, q * 8);
    float mx = p[0];
#pragma unroll
    for (int q = 1; q < 8; q++) mx = fmaxf(mx, p[q]);
    float s = 0.f;
#pragma unroll
    for (int q = 0; q < 8; q++) { p[q] = expf(p[q] - mx); s += p[q]; }
    float inv = 1.f / s;
#pragma unroll
    for (int q = 0; q < 8; q++) p[q] *= inv;
    float v1 = -1.f; int i1 = 0;
#pragma unroll
    for (int q = 0; q < 8; q++) { if (p[q] > v1) { v1 = p[q]; i1 = q; } }
    float v2 = -1.f; int i2 = 0;
#pragma unroll
    for (int q = 0; q < 8; q++) { if (q != i1 && p[q] > v2) { v2 = p[q]; i2 = q; } }
    if (lane == 0) {
        topi[2 * t] = i1; topi[2 * t + 1] = i2;
        topw[2 * t] = v1; topw[2 * t + 1] = v2;
        atomicAdd(&counts[i1], 1);
        atomicAdd(&counts[i2], 1);
    }
}

// prefix-sum + device-built tile worklist: (e<<16)|m0 ; routed tiles FIRST,
// then shared-expert (e=8) tiles. wl_n[0]=total items, wl_n[1]=routed items.
__global__ void scan_k(const int* __restrict__ counts, int* __restrict__ offsets,
                       int* __restrict__ wl, int* __restrict__ wl_n) {
    if (threadIdx.x == 0) {
        int s = 0;
        for (int e = 0; e < EEXP; e++) { offsets[e] = s; s += counts[e]; }
        offsets[EEXP] = s;
        int n = 0;
        for (int e = 0; e < EEXP; e++) {
            int Ne = counts[e];
            for (int m0 = 0; m0 < Ne; m0 += MT) wl[n++] = (e << 16) | m0;
        }
        wl_n[1] = n;                       // routed count
        for (int m0 = 0; m0 < T_TOK; m0 += MT) wl[n++] = (EEXP << 16) | m0;
        wl_n[0] = n;                       // total (<= 56)
    }
}

__global__ void build_k(const int* __restrict__ topi, const int* __restrict__ offsets,
                        int* __restrict__ cursors, int* __restrict__ rows_token,
                        int* __restrict__ rowof) {
    int t = blockIdx.x * 256 + threadIdx.x;
    if (t >= T_TOK) return;
    for (int k = 0; k < KTOP; k++) {
        int e = topi[2 * t + k];
        int pos = atomicAdd(&cursors[e], 1);
        int r = offsets[e] + pos;
        rows_token[r] = t;
        rowof[2 * t + k] = r;
    }
}

// ---------------- consolidated pre-pass ----------------
#define PREP_GRID 7232

__device__ __forceinline__ void tcast_tile(const float* __restrict__ S,
                                           unsigned short* __restrict__ Dm,
                                           int Kd, int Nn, int k0, int n0,
                                           unsigned short (*t)[132]) {
    int tid = threadIdx.x;
    int nc = (tid & 15) * 4;
    int kq = (tid >> 4) * 4;
#pragma unroll
    for (int j = 0; j < 2; j++) {
        int kb = j * 64 + kq;
        const float* p0 = S + (size_t)(k0 + kb) * Nn + n0 + nc;
        float4 q0 = *(const float4*)(p0);
        float4 q1 = *(const float4*)(p0 + (size_t)Nn);
        float4 q2 = *(const float4*)(p0 + 2 * (size_t)Nn);
        float4 q3 = *(const float4*)(p0 + 3 * (size_t)Nn);
#pragma unroll
        for (int i = 0; i < 4; i++) {
            unsigned int lo = (unsigned int)f2bf((&q0.x)[i]) | ((unsigned int)f2bf((&q1.x)[i]) << 16);
            unsigned int hi = (unsigned int)f2bf((&q2.x)[i]) | ((unsigned int)f2bf((&q3.x)[i]) << 16);
            *(uint2*)&t[nc + i][kb] = make_uint2(lo, hi);
        }
    }
    __syncthreads();
    int n = tid >> 4;
    int c = (tid & 15) * 8;
#pragma unroll
    for (int j = 0; j < 4; j++) {
        int nn = j * 16 + n;
        uint2 a = *(const uint2*)&t[nn][c];
        uint2 b = *(const uint2*)&t[nn][c + 4];
        uint4 v = make_uint4(a.x, a.y, b.x, b.y);
        *(uint4*)(Dm + (size_t)(n0 + nn) * Kd + k0 + c) = v;
    }
}

__global__ __launch_bounds__(256) void prep_k(
    const float* __restrict__ x,
    const float* __restrict__ w1, const float* __restrict__ w3,
    const float* __restrict__ sw1, const float* __restrict__ sw3,
    const float* __restrict__ sw2,
    unsigned short* __restrict__ Xb,
    unsigned short* __restrict__ W1t, unsigned short* __restrict__ W3t,
    unsigned short* __restrict__ sw1t, unsigned short* __restrict__ sw3t,
    unsigned short* __restrict__ sw2t)
{
    __shared__ __align__(16) unsigned short t[64][132];
    int b = blockIdx.x;
    if (b < 1024) {
        int i = b * 2048 + threadIdx.x * 8;
        float4 a = *(const float4*)(x + i);
        float4 c = *(const float4*)(x + i + 4);
        unsigned short o[8] = { f2bf(a.x), f2bf(a.y), f2bf(a.z), f2bf(a.w),
                                f2bf(c.x), f2bf(c.y), f2bf(c.z), f2bf(c.w) };
        *(uint4*)(Xb + i) = *(const uint4*)o;
        return;
    }
    const float* S; unsigned short* D; int Kd, Nn, k0, n0;
    if (b < 3840) {
        int idx = b - 1024, z = idx / 352, r = idx % 352;
        Kd = DDIM; Nn = HDIM;
        S = w1 + (size_t)z * DDIM * HDIM; D = W1t + (size_t)z * DDIM * HDIM;
        k0 = (r / 44) * 128; n0 = (r % 44) * 64;
    } else if (b < 6656) {
        int idx = b - 3840, z = idx / 352, r = idx % 352;
        Kd = DDIM; Nn = HDIM;
        S = w3 + (size_t)z * DDIM * HDIM; D = W3t + (size_t)z * DDIM * HDIM;
        k0 = (r / 44) * 128; n0 = (r % 44) * 64;
    } else if (b < 6848) {
        int idx = b - 6656;
        Kd = DDIM; Nn = HSDIM; S = sw1; D = sw1t;
        k0 = (idx / 24) * 128; n0 = (idx % 24) * 64;
    } else if (b < 7040) {
        int idx = b - 6848;
        Kd = DDIM; Nn = HSDIM; S = sw3; D = sw3t;
        k0 = (idx / 24) * 128; n0 = (idx % 24) * 64;
    } else {
        int idx = b - 7040;
        Kd = HSDIM; Nn = DDIM; S = sw2; D = sw2t;
        k0 = (idx / 16) * 128; n0 = (idx % 16) * 64;
    }
    tcast_tile(S, D, Kd, Nn, k0, n0, t);
}

// W [z][K][N] f32 -> Wt [z][N][K] bf16 (used for W2 after aliasing window)
__global__ __launch_bounds__(256) void tcast_k(const float* __restrict__ S,
                                               unsigned short* __restrict__ Dm,
                                               int Kd, int Nn) {
    __shared__ __align__(16) unsigned short t[64][132];
    size_t zoff = (size_t)blockIdx.z * Kd * Nn;
    tcast_tile(S + zoff, Dm + zoff, Kd, Nn, blockIdx.y * 128, blockIdx.x * 64, t);
}

// ---------------- fused up-projection: H = silu(X@W1) * (X@W3) ----------------
// tile 128(M) x 128(N), BK=64, 4 waves 2x2, per-wave 64x64 dual-accumulated.
// Live-compacted n-major logical space: nb<12 -> all items; nb>=12 -> routed only.
__global__ __launch_bounds__(256, 2) void fused_up(
    const unsigned short* __restrict__ Xb,
    const int* __restrict__ rows_token,
    const int* __restrict__ offsets,
    const unsigned short* __restrict__ W1t,   // [8][H][D] bf16
    const unsigned short* __restrict__ W3t,
    const unsigned short* __restrict__ sw1t,  // [HS][D]
    const unsigned short* __restrict__ sw3t,
    unsigned short* __restrict__ Hg,          // [4096][H]
    unsigned short* __restrict__ Hs,          // [2048][HS]
    const int* __restrict__ wl, const int* __restrict__ wl_n)
{
    int n_all = wl_n[0], n_r = wl_n[1];
    int live = NB_SH * n_all + (NB_UP - NB_SH) * n_r;
    int L = xcd_live_map(blockIdx.x, live);
    if (L < 0 || L >= live) return;
    int nb, it;
    if (L < NB_SH * n_all) { nb = L / n_all; it = L % n_all; }
    else { int L2 = L - NB_SH * n_all; nb = NB_SH + L2 / n_r; it = L2 % n_r; }
    int pk = wl[it];
    int z = pk >> 16, m0 = pk & 0xffff;
    bool sh = (z == EEXP);
    int roff, Ne, Nn;
    const unsigned short *w1, *w3;
    unsigned short* Ho;
    if (sh) { roff = 0; Ne = T_TOK; Nn = HSDIM; w1 = sw1t; w3 = sw3t; Ho = Hs; }
    else {
        roff = offsets[z]; Ne = offsets[z + 1] - roff; Nn = HDIM;
        w1 = W1t + (size_t)z * HDIM * DDIM;
        w3 = W3t + (size_t)z * HDIM * DDIM;
        Ho = Hg;
    }
    int n0 = nb * 128;
    if (n0 >= Nn) return;   // safety net (should not trigger)

    __shared__ __align__(16) unsigned short As [128 * 64];
    __shared__ __align__(16) unsigned short B1s[128 * 64];
    __shared__ __align__(16) unsigned short B3s[128 * 64];

    int tid = threadIdx.x, lane = tid & 63, wid = tid >> 6;
    int wr = wid >> 1, wc = wid & 1;          // per-wave 64 rows x 64 cols
    int sc = ((lane & 7) ^ (lane >> 3)) * 8;  // inverse-swizzled source chunk

    const unsigned short* pA[4];
    const unsigned short *pB1[4], *pB3[4];
#pragma unroll
    for (int j = 0; j < 4; j++) {
        int lr = (wid * 4 + j) * 8 + (lane >> 3);
        int gr = m0 + lr; if (gr >= Ne) gr = Ne - 1;
        int tok = sh ? gr : rows_token[roff + gr];
        pA[j]  = Xb + (size_t)tok * DDIM + sc;
        pB1[j] = w1 + (size_t)(n0 + lr) * DDIM + sc;
        pB3[j] = w3 + (size_t)(n0 + lr) * DDIM + sc;
    }

    const f32x4 fz = {0.f, 0.f, 0.f, 0.f};
    f32x4 acc1[4][4], acc3[4][4];
#pragma unroll
    for (int mi = 0; mi < 4; mi++)
#pragma unroll
        for (int nj = 0; nj < 4; nj++) { acc1[mi][nj] = fz; acc3[mi][nj] = fz; }

#pragma unroll 1
    for (int ks = 0; ks < DDIM / BK; ks++) {
        __syncthreads();
#pragma unroll
        for (int j = 0; j < 4; j++) gload16(pA[j],  As  + (wid * 4 + j) * 512);
#pragma unroll
        for (int j = 0; j < 4; j++) gload16(pB1[j], B1s + (wid * 4 + j) * 512);
#pragma unroll
        for (int j = 0; j < 4; j++) gload16(pB3[j], B3s + (wid * 4 + j) * 512);
#pragma unroll
        for (int j = 0; j < 4; j++) { pA[j] += BK; pB1[j] += BK; pB3[j] += BK; }
        __syncthreads();
        int r = lane & 15, h = lane >> 4, sw = (lane & 7) << 4;
#pragma unroll
        for (int kk = 0; kk < 2; kk++) {
            int cb = (kk * 64 + h * 16) ^ sw;
            bf16x8 a[4], b1[4], b3[4];
#pragma unroll
            for (int mi = 0; mi < 4; mi++)
                a[mi] = *(const bf16x8*)((const char*)As + (wr * 64 + mi * 16 + r) * 128 + cb);
#pragma unroll
            for (int nj = 0; nj < 4; nj++) {
                b1[nj] = *(const bf16x8*)((const char*)B1s + (wc * 64 + nj * 16 + r) * 128 + cb);
                b3[nj] = *(const bf16x8*)((const char*)B3s + (wc * 64 + nj * 16 + r) * 128 + cb);
            }
#pragma unroll
            for (int mi = 0; mi < 4; mi++)
#pragma unroll
                for (int nj = 0; nj < 4; nj++) {
                    acc1[mi][nj] = __builtin_amdgcn_mfma_f32_16x16x32_bf16(a[mi], b1[nj], acc1[mi][nj], 0, 0, 0);
                    acc3[mi][nj] = __builtin_amdgcn_mfma_f32_16x16x32_bf16(a[mi], b3[nj], acc3[mi][nj], 0, 0, 0);
                }
        }
    }
    int r = lane & 15, h = lane >> 4;
#pragma unroll
    for (int mi = 0; mi < 4; mi++) {
#pragma unroll
        for (int nj = 0; nj < 4; nj++) {
            int col = n0 + wc * 64 + nj * 16 + r;
#pragma unroll
            for (int j = 0; j < 4; j++) {
                int row = wr * 64 + mi * 16 + h * 4 + j;
                if (m0 + row < Ne) {
                    float aa = acc1[mi][nj][j], bb = acc3[mi][nj][j];
                    float hv = (aa / (1.f + expf(-aa))) * bb;
                    Ho[(size_t)(roff + m0 + row) * Nn + col] = f2bf(hv);
                }
            }
        }
    }
}

// ---------------- down-projection: Y = H @ W2 ----------------
// tile 128(M) x 128(N), BK=64; live = NB_DN * n_all (all items valid for all nb).
__global__ __launch_bounds__(256) void gemm2(
    const unsigned short* __restrict__ Hg,
    const unsigned short* __restrict__ Hs,
    const unsigned short* __restrict__ W2t,   // [8][D][H] bf16
    const unsigned short* __restrict__ sw2t,  // [D][HS]
    const int* __restrict__ offsets,
    float* __restrict__ Yg,
    float* __restrict__ out,
    const int* __restrict__ wl, const int* __restrict__ wl_n)
{
    int n_all = wl_n[0];
    int live = NB_DN * n_all;
    int L = xcd_live_map(blockIdx.x, live);
    if (L < 0 || L >= live) return;
    int nb = L / n_all, it = L % n_all;
    int pk = wl[it];
    int z = pk >> 16, m0 = pk & 0xffff;
    bool sh = (z == EEXP);
    int roff, Ne, Kd;
    const unsigned short *Ab, *Bb;
    float* Yo;
    if (sh) { roff = 0; Ne = T_TOK; Kd = HSDIM; Ab = Hs; Bb = sw2t; Yo = out; }
    else {
        roff = offsets[z]; Ne = offsets[z + 1] - roff; Kd = HDIM;
        Ab = Hg + (size_t)roff * HDIM;
        Bb = W2t + (size_t)z * DDIM * HDIM;
        Yo = Yg + (size_t)roff * DDIM;
    }
    int n0 = nb * 128;

    __shared__ __align__(16) unsigned short As[128 * 64];
    __shared__ __align__(16) unsigned short Bs[128 * 64];

    int tid = threadIdx.x, lane = tid & 63, wid = tid >> 6;
    int wr = wid >> 1, wc = wid & 1;
    int sc = ((lane & 7) ^ (lane >> 3)) * 8;

    const unsigned short* pA[4];
    const unsigned short* pB[4];
#pragma unroll
    for (int j = 0; j < 4; j++) {
        int lr = (wid * 4 + j) * 8 + (lane >> 3);
        int gr = m0 + lr; if (gr >= Ne) gr = Ne - 1;
        pA[j] = Ab + (size_t)gr * Kd + sc;
        pB[j] = Bb + (size_t)(n0 + lr) * Kd + sc;
    }

    const f32x4 fz = {0.f, 0.f, 0.f, 0.f};
    f32x4 acc[4][4];
#pragma unroll
    for (int mi = 0; mi < 4; mi++)
#pragma unroll
        for (int nj = 0; nj < 4; nj++) acc[mi][nj] = fz;

    int nks = Kd / BK;
#pragma unroll 1
    for (int ks = 0; ks < nks; ks++) {
        __syncthreads();
#pragma unroll
        for (int j = 0; j < 4; j++) gload16(pA[j], As + (wid * 4 + j) * 512);
#pragma unroll
        for (int j = 0; j < 4; j++) gload16(pB[j], Bs + (wid * 4 + j) * 512);
#pragma unroll
        for (int j = 0; j < 4; j++) { pA[j] += BK; pB[j] += BK; }
        __syncthreads();
        int r = lane & 15, h = lane >> 4, sw = (lane & 7) << 4;
#pragma unroll
        for (int kk = 0; kk < 2; kk++) {
            int cb = (kk * 64 + h * 16) ^ sw;
            bf16x8 a[4], b[4];
#pragma unroll
            for (int mi = 0; mi < 4; mi++)
                a[mi] = *(const bf16x8*)((const char*)As + (wr * 64 + mi * 16 + r) * 128 + cb);
#pragma unroll
            for (int nj = 0; nj < 4; nj++)
                b[nj] = *(const bf16x8*)((const char*)Bs + (wc * 64 + nj * 16 + r) * 128 + cb);
#pragma unroll
            for (int mi = 0; mi < 4; mi++)
#pragma unroll
                for (int nj = 0; nj < 4; nj++)
                    acc[mi][nj] = __builtin_amdgcn_mfma_f32_16x16x32_bf16(a[mi], b[nj], acc[mi][nj], 0, 0, 0);
        }
    }
    int r = lane & 15, h = lane >> 4;
#pragma unroll
    for (int mi = 0; mi < 4; mi++) {
#pragma unroll
        for (int nj = 0; nj < 4; nj++) {
            int col = n0 + wc * 64 + nj * 16 + r;
#pragma unroll
            for (int j = 0; j < 4; j++) {
                int row = wr * 64 + mi * 16 + h * 4 + j;
                if (m0 + row < Ne)
                    Yo[(size_t)(m0 + row) * DDIM + col] = acc[mi][nj][j];
            }
        }
    }
}

// ---------------- final combine ----------------
__global__ void combine_k(float* __restrict__ out, const float* __restrict__ Yg,
                          const int* __restrict__ rowof, const float* __restrict__ topw) {
    int idx = blockIdx.x * 256 + threadIdx.x;
    int t = idx >> 8;
    int dq = (idx & 255) << 2;
    int r0 = rowof[2 * t], r1 = rowof[2 * t + 1];
    float g0 = topw[2 * t], g1 = topw[2 * t + 1];
    float* op = out + (size_t)t * DDIM + dq;
    float4 o = *(float4*)op;
    float4 a = *(const float4*)(Yg + (size_t)r0 * DDIM + dq);
    float4 b = *(const float4*)(Yg + (size_t)r1 * DDIM + dq);
    o.x += g0 * a.x + g1 * b.x;
    o.y += g0 * a.y + g1 * b.y;
    o.z += g0 * a.z + g1 * b.z;
    o.w += g0 * a.w + g1 * b.w;
    *(float4*)op = o;
}

// ---------------- launch ----------------
extern "C" void kernel_launch(void* const* d_in, const int* in_sizes, int n_in,
                              void* d_out, int out_size, void* d_ws, size_t ws_size,
                              hipStream_t stream) {
    const float* x   = (const float*)d_in[0];
    const float* gw  = (const float*)d_in[1];
    const float* w1  = (const float*)d_in[2];
    const float* w3  = (const float*)d_in[3];
    const float* w2  = (const float*)d_in[4];
    const float* sw1 = (const float*)d_in[5];
    const float* sw3 = (const float*)d_in[6];
    const float* sw2 = (const float*)d_in[7];
    float* out = (float*)d_out;
    char* ws = (char*)d_ws;

    const size_t MB = 1048576;
    int*   counts     = (int*)(ws);
    int*   offsets    = (int*)(ws + 64);
    int*   cursors    = (int*)(ws + 128);
    int*   wl_n       = (int*)(ws + 192);     // [0]=total, [1]=routed
    int*   wl         = (int*)(ws + 256);
    int*   topi       = (int*)(ws + 512);
    float* topw       = (float*)(ws + 16896);
    int*   rows_token = (int*)(ws + 33280);
    int*   rowof      = (int*)(ws + 49664);
    unsigned short* Xb   = (unsigned short*)(ws + 1 * MB);    // 4 MB
    unsigned short* sw1t = (unsigned short*)(ws + 6 * MB);    // 3 MB
    unsigned short* sw3t = (unsigned short*)(ws + 9 * MB);    // 3 MB
    unsigned short* sw2t = (unsigned short*)(ws + 12 * MB);   // 3 MB
    unsigned short* Hg   = (unsigned short*)(ws + 16 * MB);   // 22 MB
    float*          Yg   = (float*)(ws + 40 * MB);            // 16 MB
    unsigned short* Hs   = (unsigned short*)(ws + 56 * MB);   // 6 MB
    unsigned short* W1t  = (unsigned short*)(ws + 64 * MB);   // 44 MB
    unsigned short* W3t  = (unsigned short*)(ws + 108 * MB);  // 44 MB (ends 152 MB)
    unsigned short* W2t  = W1t;  // aliased: converted after fused_up consumes W1t

    // routing
    init_k<<<1, 64, 0, stream>>>(counts, cursors);
    gate_k<<<T_TOK / 4, 256, 0, stream>>>(x, gw, topi, topw, counts);
    scan_k<<<1, 64, 0, stream>>>(counts, offsets, wl, wl_n);
    build_k<<<T_TOK / 256, 256, 0, stream>>>(topi, offsets, cursors, rows_token, rowof);

    // consolidated pre-pass: xcast + all transposes except w2
    prep_k<<<PREP_GRID, 256, 0, stream>>>(x, w1, w3, sw1, sw3, sw2,
                                          Xb, W1t, W3t, sw1t, sw3t, sw2t);

    // up-projection (live-compacted n-major grid)
    fused_up<<<GRID_UP, 256, 0, stream>>>(
        Xb, rows_token, offsets, W1t, W3t, sw1t, sw3t, Hg, Hs, wl, wl_n);

    // W2 transpose (into aliased region, after fused_up is done with W1t)
    tcast_k<<<dim3(DDIM / 64, HDIM / 128, EEXP), 256, 0, stream>>>(w2, W2t, HDIM, DDIM);

    // down-projection (routed -> Yg, shared -> out direct)
    gemm2<<<GRID_DN, 256, 0, stream>>>(
        Hg, Hs, W2t, sw2t, offsets, Yg, out, wl, wl_n);

    // out = shared + g0*y0 + g1*y1
    combine_k<<<(T_TOK * DDIM / 4) / 256, 256, 0, stream>>>(out, Yg, rowof, topw);
}

// Round 7
// 291.179 us; speedup vs baseline: 1.2220x; 1.0105x over previous
//
#include <hip/hip_runtime.h>
#include <hip/hip_bf16.h>

// Problem constants
#define T_TOK 2048      // B*S
#define DDIM  1024
#define EEXP  8
#define KTOP  2
#define HDIM  2816
#define HSDIM 1536
#define BK    64
#define MT    128       // GEMM m-tile
#define NB_UP 22        // HDIM/128
#define NB_SH 12        // HSDIM/128
#define NB_DN 8         // DDIM/128
#define GRID_UP 1072    // max live: 12*56 + 10*40
#define GRID_DN 448     // 8*56

typedef float f32x4 __attribute__((ext_vector_type(4)));
typedef short bf16x8 __attribute__((ext_vector_type(8)));

__device__ __forceinline__ unsigned short f2bf(float f) {
    __hip_bfloat16 h = __float2bfloat16(f);
    return __builtin_bit_cast(unsigned short, h);
}

// async global->LDS, 16B per lane; LDS dest = wave-uniform base + lane*16
__device__ __forceinline__ void gload16(const unsigned short* g, unsigned short* l) {
    __builtin_amdgcn_global_load_lds(
        (const __attribute__((address_space(1))) unsigned int*)g,
        (__attribute__((address_space(3))) unsigned int*)l, 16, 0, 0);
}

// Bijective chunked XCD remap over a RUNTIME live count (m204 general form).
__device__ __forceinline__ int xcd_live_map(int i, int n) {
    int q = n >> 3, r = n & 7;
    int xcd = i & 7, loc = i >> 3;
    int cap = q + (xcd < r ? 1 : 0);
    if (loc >= cap) return -1;
    return (xcd < r ? xcd * (q + 1) : r * (q + 1) + (xcd - r) * q) + loc;
}

// ---------------- small routing kernels ----------------

__global__ void init_k(int* counts, int* cursors) {
    if (threadIdx.x < EEXP) { counts[threadIdx.x] = 0; cursors[threadIdx.x] = 0; }
}

__global__ void gate_k(const float* __restrict__ X, const float* __restrict__ GW,
                       int* __restrict__ topi, float* __restrict__ topw,
                       int* __restrict__ counts) {
    int lane = threadIdx.x & 63;
    int t = blockIdx.x * 4 + (threadIdx.x >> 6);
    int e  = lane >> 3;
    int c8 = lane & 7;
    const float* xr = X + (size_t)t * DDIM;
    const float* gr = GW + (size_t)e * DDIM;
    float acc = 0.f;
#pragma unroll 8
    for (int j = 0; j < 32; j++) {
        int d = (c8 + 8 * j) * 4;
        float4 xv = *(const float4*)(xr + d);
        float4 gv = *(const float4*)(gr + d);
        acc += xv.x * gv.x + xv.y * gv.y + xv.z * gv.z + xv.w * gv.w;
    }
    acc += __shfl_xor(acc, 1);
    acc += __shfl_xor(acc, 2);
    acc += __shfl_xor(acc, 4);
    float p[8];
#pragma unroll
    for (int q = 0; q < 8; q++) p[q] = __shfl(acc, q * 8);
    float mx = p[0];
#pragma unroll
    for (int q = 1; q < 8; q++) mx = fmaxf(mx, p[q]);
    float s = 0.f;
#pragma unroll
    for (int q = 0; q < 8; q++) { p[q] = expf(p[q] - mx); s += p[q]; }
    float inv = 1.f / s;
#pragma unroll
    for (int q = 0; q < 8; q++) p[q] *= inv;
    float v1 = -1.f; int i1 = 0;
#pragma unroll
    for (int q = 0; q < 8; q++) { if (p[q] > v1) { v1 = p[q]; i1 = q; } }
    float v2 = -1.f; int i2 = 0;
#pragma unroll
    for (int q = 0; q < 8; q++) { if (q != i1 && p[q] > v2) { v2 = p[q]; i2 = q; } }
    if (lane == 0) {
        topi[2 * t] = i1; topi[2 * t + 1] = i2;
        topw[2 * t] = v1; topw[2 * t + 1] = v2;
        atomicAdd(&counts[i1], 1);
        atomicAdd(&counts[i2], 1);
    }
}

// prefix-sum + device-built tile worklist: (e<<16)|m0 ; routed tiles FIRST,
// then shared-expert (e=8) tiles. wl_n[0]=total items, wl_n[1]=routed items.
__global__ void scan_k(const int* __restrict__ counts, int* __restrict__ offsets,
                       int* __restrict__ wl, int* __restrict__ wl_n) {
    if (threadIdx.x == 0) {
        int s = 0;
        for (int e = 0; e < EEXP; e++) { offsets[e] = s; s += counts[e]; }
        offsets[EEXP] = s;
        int n = 0;
        for (int e = 0; e < EEXP; e++) {
            int Ne = counts[e];
            for (int m0 = 0; m0 < Ne; m0 += MT) wl[n++] = (e << 16) | m0;
        }
        wl_n[1] = n;                       // routed count
        for (int m0 = 0; m0 < T_TOK; m0 += MT) wl[n++] = (EEXP << 16) | m0;
        wl_n[0] = n;                       // total (<= 56)
    }
}

__global__ void build_k(const int* __restrict__ topi, const int* __restrict__ offsets,
                        int* __restrict__ cursors, int* __restrict__ rows_token,
                        int* __restrict__ rowof) {
    int t = blockIdx.x * 256 + threadIdx.x;
    if (t >= T_TOK) return;
    for (int k = 0; k < KTOP; k++) {
        int e = topi[2 * t + k];
        int pos = atomicAdd(&cursors[e], 1);
        int r = offsets[e] + pos;
        rows_token[r] = t;
        rowof[2 * t + k] = r;
    }
}

// ---------------- consolidated pre-pass ----------------
#define PREP_GRID 7232

// 128(k) x 64(n) f32->bf16 transpose tile. ALL 8 global loads hoisted into
// registers BEFORE any conversion/LDS traffic: 128B/thread in flight
// (round-6 post-mortem: VGPR=20 build serialized loads -> 2.2 TB/s latency-bound).
__device__ __forceinline__ void tcast_tile(const float* __restrict__ S,
                                           unsigned short* __restrict__ Dm,
                                           int Kd, int Nn, int k0, int n0,
                                           unsigned short (*t)[132]) {
    int tid = threadIdx.x;
    int nc = (tid & 15) * 4;
    int kq = (tid >> 4) * 4;
    f32x4 q0a, q1a, q2a, q3a, q0b, q1b, q2b, q3b;
    {
        const float* pa = S + (size_t)(k0 + kq) * Nn + n0 + nc;
        const float* pb = S + (size_t)(k0 + 64 + kq) * Nn + n0 + nc;
        q0a = *(const f32x4*)(pa);
        q1a = *(const f32x4*)(pa + (size_t)Nn);
        q2a = *(const f32x4*)(pa + 2 * (size_t)Nn);
        q3a = *(const f32x4*)(pa + 3 * (size_t)Nn);
        q0b = *(const f32x4*)(pb);
        q1b = *(const f32x4*)(pb + (size_t)Nn);
        q2b = *(const f32x4*)(pb + 2 * (size_t)Nn);
        q3b = *(const f32x4*)(pb + 3 * (size_t)Nn);
    }
#pragma unroll
    for (int i = 0; i < 4; i++) {
        unsigned int lo = (unsigned int)f2bf(q0a[i]) | ((unsigned int)f2bf(q1a[i]) << 16);
        unsigned int hi = (unsigned int)f2bf(q2a[i]) | ((unsigned int)f2bf(q3a[i]) << 16);
        *(uint2*)&t[nc + i][kq] = make_uint2(lo, hi);
    }
#pragma unroll
    for (int i = 0; i < 4; i++) {
        unsigned int lo = (unsigned int)f2bf(q0b[i]) | ((unsigned int)f2bf(q1b[i]) << 16);
        unsigned int hi = (unsigned int)f2bf(q2b[i]) | ((unsigned int)f2bf(q3b[i]) << 16);
        *(uint2*)&t[nc + i][64 + kq] = make_uint2(lo, hi);
    }
    __syncthreads();
    int n = tid >> 4;
    int c = (tid & 15) * 8;
#pragma unroll
    for (int j = 0; j < 4; j++) {
        int nn = j * 16 + n;
        uint2 a = *(const uint2*)&t[nn][c];
        uint2 b = *(const uint2*)&t[nn][c + 4];
        uint4 v = make_uint4(a.x, a.y, b.x, b.y);
        *(uint4*)(Dm + (size_t)(n0 + nn) * Kd + k0 + c) = v;
    }
}

__global__ __launch_bounds__(256) void prep_k(
    const float* __restrict__ x,
    const float* __restrict__ w1, const float* __restrict__ w3,
    const float* __restrict__ sw1, const float* __restrict__ sw3,
    const float* __restrict__ sw2,
    unsigned short* __restrict__ Xb,
    unsigned short* __restrict__ W1t, unsigned short* __restrict__ W3t,
    unsigned short* __restrict__ sw1t, unsigned short* __restrict__ sw3t,
    unsigned short* __restrict__ sw2t)
{
    __shared__ __align__(16) unsigned short t[64][132];
    int b = blockIdx.x;
    if (b < 1024) {
        int i = b * 2048 + threadIdx.x * 8;
        float4 a = *(const float4*)(x + i);
        float4 c = *(const float4*)(x + i + 4);
        unsigned short o[8] = { f2bf(a.x), f2bf(a.y), f2bf(a.z), f2bf(a.w),
                                f2bf(c.x), f2bf(c.y), f2bf(c.z), f2bf(c.w) };
        *(uint4*)(Xb + i) = *(const uint4*)o;
        return;
    }
    const float* S; unsigned short* D; int Kd, Nn, k0, n0;
    if (b < 3840) {
        int idx = b - 1024, z = idx / 352, r = idx % 352;
        Kd = DDIM; Nn = HDIM;
        S = w1 + (size_t)z * DDIM * HDIM; D = W1t + (size_t)z * DDIM * HDIM;
        k0 = (r / 44) * 128; n0 = (r % 44) * 64;
    } else if (b < 6656) {
        int idx = b - 3840, z = idx / 352, r = idx % 352;
        Kd = DDIM; Nn = HDIM;
        S = w3 + (size_t)z * DDIM * HDIM; D = W3t + (size_t)z * DDIM * HDIM;
        k0 = (r / 44) * 128; n0 = (r % 44) * 64;
    } else if (b < 6848) {
        int idx = b - 6656;
        Kd = DDIM; Nn = HSDIM; S = sw1; D = sw1t;
        k0 = (idx / 24) * 128; n0 = (idx % 24) * 64;
    } else if (b < 7040) {
        int idx = b - 6848;
        Kd = DDIM; Nn = HSDIM; S = sw3; D = sw3t;
        k0 = (idx / 24) * 128; n0 = (idx % 24) * 64;
    } else {
        int idx = b - 7040;
        Kd = HSDIM; Nn = DDIM; S = sw2; D = sw2t;
        k0 = (idx / 16) * 128; n0 = (idx % 16) * 64;
    }
    tcast_tile(S, D, Kd, Nn, k0, n0, t);
}

// W [z][K][N] f32 -> Wt [z][N][K] bf16 (used for W2 after aliasing window)
__global__ __launch_bounds__(256) void tcast_k(const float* __restrict__ S,
                                               unsigned short* __restrict__ Dm,
                                               int Kd, int Nn) {
    __shared__ __align__(16) unsigned short t[64][132];
    size_t zoff = (size_t)blockIdx.z * Kd * Nn;
    tcast_tile(S + zoff, Dm + zoff, Kd, Nn, blockIdx.y * 128, blockIdx.x * 64, t);
}

// ---------------- fused up-projection: H = silu(X@W1) * (X@W3) ----------------
// tile 128(M) x 128(N), BK=64, 4 waves 2x2, per-wave 64x64 dual-accumulated.
// Live-compacted n-major logical space: nb<12 -> all items; nb>=12 -> routed only.
__global__ __launch_bounds__(256, 2) void fused_up(
    const unsigned short* __restrict__ Xb,
    const int* __restrict__ rows_token,
    const int* __restrict__ offsets,
    const unsigned short* __restrict__ W1t,   // [8][H][D] bf16
    const unsigned short* __restrict__ W3t,
    const unsigned short* __restrict__ sw1t,  // [HS][D]
    const unsigned short* __restrict__ sw3t,
    unsigned short* __restrict__ Hg,          // [4096][H]
    unsigned short* __restrict__ Hs,          // [2048][HS]
    const int* __restrict__ wl, const int* __restrict__ wl_n)
{
    int n_all = wl_n[0], n_r = wl_n[1];
    int live = NB_SH * n_all + (NB_UP - NB_SH) * n_r;
    int L = xcd_live_map(blockIdx.x, live);
    if (L < 0 || L >= live) return;
    int nb, it;
    if (L < NB_SH * n_all) { nb = L / n_all; it = L % n_all; }
    else { int L2 = L - NB_SH * n_all; nb = NB_SH + L2 / n_r; it = L2 % n_r; }
    int pk = wl[it];
    int z = pk >> 16, m0 = pk & 0xffff;
    bool sh = (z == EEXP);
    int roff, Ne, Nn;
    const unsigned short *w1, *w3;
    unsigned short* Ho;
    if (sh) { roff = 0; Ne = T_TOK; Nn = HSDIM; w1 = sw1t; w3 = sw3t; Ho = Hs; }
    else {
        roff = offsets[z]; Ne = offsets[z + 1] - roff; Nn = HDIM;
        w1 = W1t + (size_t)z * HDIM * DDIM;
        w3 = W3t + (size_t)z * HDIM * DDIM;
        Ho = Hg;
    }
    int n0 = nb * 128;
    if (n0 >= Nn) return;   // safety net (should not trigger)

    __shared__ __align__(16) unsigned short As [128 * 64];
    __shared__ __align__(16) unsigned short B1s[128 * 64];
    __shared__ __align__(16) unsigned short B3s[128 * 64];

    int tid = threadIdx.x, lane = tid & 63, wid = tid >> 6;
    int wr = wid >> 1, wc = wid & 1;          // per-wave 64 rows x 64 cols
    int sc = ((lane & 7) ^ (lane >> 3)) * 8;  // inverse-swizzled source chunk

    const unsigned short* pA[4];
    const unsigned short *pB1[4], *pB3[4];
#pragma unroll
    for (int j = 0; j < 4; j++) {
        int lr = (wid * 4 + j) * 8 + (lane >> 3);
        int gr = m0 + lr; if (gr >= Ne) gr = Ne - 1;
        int tok = sh ? gr : rows_token[roff + gr];
        pA[j]  = Xb + (size_t)tok * DDIM + sc;
        pB1[j] = w1 + (size_t)(n0 + lr) * DDIM + sc;
        pB3[j] = w3 + (size_t)(n0 + lr) * DDIM + sc;
    }

    const f32x4 fz = {0.f, 0.f, 0.f, 0.f};
    f32x4 acc1[4][4], acc3[4][4];
#pragma unroll
    for (int mi = 0; mi < 4; mi++)
#pragma unroll
        for (int nj = 0; nj < 4; nj++) { acc1[mi][nj] = fz; acc3[mi][nj] = fz; }

#pragma unroll 1
    for (int ks = 0; ks < DDIM / BK; ks++) {
        __syncthreads();
#pragma unroll
        for (int j = 0; j < 4; j++) gload16(pA[j],  As  + (wid * 4 + j) * 512);
#pragma unroll
        for (int j = 0; j < 4; j++) gload16(pB1[j], B1s + (wid * 4 + j) * 512);
#pragma unroll
        for (int j = 0; j < 4; j++) gload16(pB3[j], B3s + (wid * 4 + j) * 512);
#pragma unroll
        for (int j = 0; j < 4; j++) { pA[j] += BK; pB1[j] += BK; pB3[j] += BK; }
        __syncthreads();
        int r = lane & 15, h = lane >> 4, sw = (lane & 7) << 4;
#pragma unroll
        for (int kk = 0; kk < 2; kk++) {
            int cb = (kk * 64 + h * 16) ^ sw;
            bf16x8 a[4], b1[4], b3[4];
#pragma unroll
            for (int mi = 0; mi < 4; mi++)
                a[mi] = *(const bf16x8*)((const char*)As + (wr * 64 + mi * 16 + r) * 128 + cb);
#pragma unroll
            for (int nj = 0; nj < 4; nj++) {
                b1[nj] = *(const bf16x8*)((const char*)B1s + (wc * 64 + nj * 16 + r) * 128 + cb);
                b3[nj] = *(const bf16x8*)((const char*)B3s + (wc * 64 + nj * 16 + r) * 128 + cb);
            }
#pragma unroll
            for (int mi = 0; mi < 4; mi++)
#pragma unroll
                for (int nj = 0; nj < 4; nj++) {
                    acc1[mi][nj] = __builtin_amdgcn_mfma_f32_16x16x32_bf16(a[mi], b1[nj], acc1[mi][nj], 0, 0, 0);
                    acc3[mi][nj] = __builtin_amdgcn_mfma_f32_16x16x32_bf16(a[mi], b3[nj], acc3[mi][nj], 0, 0, 0);
                }
        }
    }
    int r = lane & 15, h = lane >> 4;
#pragma unroll
    for (int mi = 0; mi < 4; mi++) {
#pragma unroll
        for (int nj = 0; nj < 4; nj++) {
            int col = n0 + wc * 64 + nj * 16 + r;
#pragma unroll
            for (int j = 0; j < 4; j++) {
                int row = wr * 64 + mi * 16 + h * 4 + j;
                if (m0 + row < Ne) {
                    float aa = acc1[mi][nj][j], bb = acc3[mi][nj][j];
                    float hv = (aa / (1.f + expf(-aa))) * bb;
                    Ho[(size_t)(roff + m0 + row) * Nn + col] = f2bf(hv);
                }
            }
        }
    }
}

// ---------------- down-projection: Y = H @ W2 ----------------
// tile 128(M) x 128(N), BK=64; live = NB_DN * n_all (all items valid for all nb).
__global__ __launch_bounds__(256) void gemm2(
    const unsigned short* __restrict__ Hg,
    const unsigned short* __restrict__ Hs,
    const unsigned short* __restrict__ W2t,   // [8][D][H] bf16
    const unsigned short* __restrict__ sw2t,  // [D][HS]
    const int* __restrict__ offsets,
    float* __restrict__ Yg,
    float* __restrict__ out,
    const int* __restrict__ wl, const int* __restrict__ wl_n)
{
    int n_all = wl_n[0];
    int live = NB_DN * n_all;
    int L = xcd_live_map(blockIdx.x, live);
    if (L < 0 || L >= live) return;
    int nb = L / n_all, it = L % n_all;
    int pk = wl[it];
    int z = pk >> 16, m0 = pk & 0xffff;
    bool sh = (z == EEXP);
    int roff, Ne, Kd;
    const unsigned short *Ab, *Bb;
    float* Yo;
    if (sh) { roff = 0; Ne = T_TOK; Kd = HSDIM; Ab = Hs; Bb = sw2t; Yo = out; }
    else {
        roff = offsets[z]; Ne = offsets[z + 1] - roff; Kd = HDIM;
        Ab = Hg + (size_t)roff * HDIM;
        Bb = W2t + (size_t)z * DDIM * HDIM;
        Yo = Yg + (size_t)roff * DDIM;
    }
    int n0 = nb * 128;

    __shared__ __align__(16) unsigned short As[128 * 64];
    __shared__ __align__(16) unsigned short Bs[128 * 64];

    int tid = threadIdx.x, lane = tid & 63, wid = tid >> 6;
    int wr = wid >> 1, wc = wid & 1;
    int sc = ((lane & 7) ^ (lane >> 3)) * 8;

    const unsigned short* pA[4];
    const unsigned short* pB[4];
#pragma unroll
    for (int j = 0; j < 4; j++) {
        int lr = (wid * 4 + j) * 8 + (lane >> 3);
        int gr = m0 + lr; if (gr >= Ne) gr = Ne - 1;
        pA[j] = Ab + (size_t)gr * Kd + sc;
        pB[j] = Bb + (size_t)(n0 + lr) * Kd + sc;
    }

    const f32x4 fz = {0.f, 0.f, 0.f, 0.f};
    f32x4 acc[4][4];
#pragma unroll
    for (int mi = 0; mi < 4; mi++)
#pragma unroll
        for (int nj = 0; nj < 4; nj++) acc[mi][nj] = fz;

    int nks = Kd / BK;
#pragma unroll 1
    for (int ks = 0; ks < nks; ks++) {
        __syncthreads();
#pragma unroll
        for (int j = 0; j < 4; j++) gload16(pA[j], As + (wid * 4 + j) * 512);
#pragma unroll
        for (int j = 0; j < 4; j++) gload16(pB[j], Bs + (wid * 4 + j) * 512);
#pragma unroll
        for (int j = 0; j < 4; j++) { pA[j] += BK; pB[j] += BK; }
        __syncthreads();
        int r = lane & 15, h = lane >> 4, sw = (lane & 7) << 4;
#pragma unroll
        for (int kk = 0; kk < 2; kk++) {
            int cb = (kk * 64 + h * 16) ^ sw;
            bf16x8 a[4], b[4];
#pragma unroll
            for (int mi = 0; mi < 4; mi++)
                a[mi] = *(const bf16x8*)((const char*)As + (wr * 64 + mi * 16 + r) * 128 + cb);
#pragma unroll
            for (int nj = 0; nj < 4; nj++)
                b[nj] = *(const bf16x8*)((const char*)Bs + (wc * 64 + nj * 16 + r) * 128 + cb);
#pragma unroll
            for (int mi = 0; mi < 4; mi++)
#pragma unroll
                for (int nj = 0; nj < 4; nj++)
                    acc[mi][nj] = __builtin_amdgcn_mfma_f32_16x16x32_bf16(a[mi], b[nj], acc[mi][nj], 0, 0, 0);
        }
    }
    int r = lane & 15, h = lane >> 4;
#pragma unroll
    for (int mi = 0; mi < 4; mi++) {
#pragma unroll
        for (int nj = 0; nj < 4; nj++) {
            int col = n0 + wc * 64 + nj * 16 + r;
#pragma unroll
            for (int j = 0; j < 4; j++) {
                int row = wr * 64 + mi * 16 + h * 4 + j;
                if (m0 + row < Ne)
                    Yo[(size_t)(m0 + row) * DDIM + col] = acc[mi][nj][j];
            }
        }
    }
}

// ---------------- final combine ----------------
__global__ void combine_k(float* __restrict__ out, const float* __restrict__ Yg,
                          const int* __restrict__ rowof, const float* __restrict__ topw) {
    int idx = blockIdx.x * 256 + threadIdx.x;
    int t = idx >> 8;
    int dq = (idx & 255) << 2;
    int r0 = rowof[2 * t], r1 = rowof[2 * t + 1];
    float g0 = topw[2 * t], g1 = topw[2 * t + 1];
    float* op = out + (size_t)t * DDIM + dq;
    float4 o = *(float4*)op;
    float4 a = *(const float4*)(Yg + (size_t)r0 * DDIM + dq);
    float4 b = *(const float4*)(Yg + (size_t)r1 * DDIM + dq);
    o.x += g0 * a.x + g1 * b.x;
    o.y += g0 * a.y + g1 * b.y;
    o.z += g0 * a.z + g1 * b.z;
    o.w += g0 * a.w + g1 * b.w;
    *(float4*)op = o;
}

// ---------------- launch ----------------
extern "C" void kernel_launch(void* const* d_in, const int* in_sizes, int n_in,
                              void* d_out, int out_size, void* d_ws, size_t ws_size,
                              hipStream_t stream) {
    const float* x   = (const float*)d_in[0];
    const float* gw  = (const float*)d_in[1];
    const float* w1  = (const float*)d_in[2];
    const float* w3  = (const float*)d_in[3];
    const float* w2  = (const float*)d_in[4];
    const float* sw1 = (const float*)d_in[5];
    const float* sw3 = (const float*)d_in[6];
    const float* sw2 = (const float*)d_in[7];
    float* out = (float*)d_out;
    char* ws = (char*)d_ws;

    const size_t MB = 1048576;
    int*   counts     = (int*)(ws);
    int*   offsets    = (int*)(ws + 64);
    int*   cursors    = (int*)(ws + 128);
    int*   wl_n       = (int*)(ws + 192);     // [0]=total, [1]=routed
    int*   wl         = (int*)(ws + 256);
    int*   topi       = (int*)(ws + 512);
    float* topw       = (float*)(ws + 16896);
    int*   rows_token = (int*)(ws + 33280);
    int*   rowof      = (int*)(ws + 49664);
    unsigned short* Xb   = (unsigned short*)(ws + 1 * MB);    // 4 MB
    unsigned short* sw1t = (unsigned short*)(ws + 6 * MB);    // 3 MB
    unsigned short* sw3t = (unsigned short*)(ws + 9 * MB);    // 3 MB
    unsigned short* sw2t = (unsigned short*)(ws + 12 * MB);   // 3 MB
    unsigned short* Hg   = (unsigned short*)(ws + 16 * MB);   // 22 MB
    float*          Yg   = (float*)(ws + 40 * MB);            // 16 MB
    unsigned short* Hs   = (unsigned short*)(ws + 56 * MB);   // 6 MB
    unsigned short* W1t  = (unsigned short*)(ws + 64 * MB);   // 44 MB
    unsigned short* W3t  = (unsigned short*)(ws + 108 * MB);  // 44 MB (ends 152 MB)
    unsigned short* W2t  = W1t;  // aliased: converted after fused_up consumes W1t

    // routing
    init_k<<<1, 64, 0, stream>>>(counts, cursors);
    gate_k<<<T_TOK / 4, 256, 0, stream>>>(x, gw, topi, topw, counts);
    scan_k<<<1, 64, 0, stream>>>(counts, offsets, wl, wl_n);
    build_k<<<T_TOK / 256, 256, 0, stream>>>(topi, offsets, cursors, rows_token, rowof);

    // consolidated pre-pass: xcast + all transposes except w2
    prep_k<<<PREP_GRID, 256, 0, stream>>>(x, w1, w3, sw1, sw3, sw2,
                                          Xb, W1t, W3t, sw1t, sw3t, sw2t);

    // up-projection (live-compacted n-major grid)
    fused_up<<<GRID_UP, 256, 0, stream>>>(
        Xb, rows_token, offsets, W1t, W3t, sw1t, sw3t, Hg, Hs, wl, wl_n);

    // W2 transpose (into aliased region, after fused_up is done with W1t)
    tcast_k<<<dim3(DDIM / 64, HDIM / 128, EEXP), 256, 0, stream>>>(w2, W2t, HDIM, DDIM);

    // down-projection (routed -> Yg, shared -> out direct)
    gemm2<<<GRID_DN, 256, 0, stream>>>(
        Hg, Hs, W2t, sw2t, offsets, Yg, out, wl, wl_n);

    // out = shared + g0*y0 + g1*y1
    combine_k<<<(T_TOK * DDIM / 4) / 256, 256, 0, stream>>>(out, Yg, rowof, topw);
}